// Round 1
// baseline (722.079 us; speedup 1.0000x reference)
//
#include <hip/hip_runtime.h>

typedef __bf16 bf16x8 __attribute__((ext_vector_type(8)));
typedef float  f32x4  __attribute__((ext_vector_type(4)));

#define MFMA16(a,b,c) __builtin_amdgcn_mfma_f32_16x16x32_bf16((a),(b),(c),0,0,0)

#define AS1(p) (const __attribute__((address_space(1))) void*)(p)
#define AS3(p) (__attribute__((address_space(3))) void*)(p)
#define GLL16(g, l) __builtin_amdgcn_global_load_lds(AS1(g), AS3(l), 16, 0, 0)

// B=4, N=2048, H=12, hd=64, D=768, M=B*N=8192

// ---------------- x -> (xh, xl) split bf16 ----------------
__global__ __launch_bounds__(256) void k_conv_x(const float* __restrict__ x,
                                                __bf16* __restrict__ xh,
                                                __bf16* __restrict__ xl) {
  int i = blockIdx.x * 256 + threadIdx.x;   // 786432 threads * 8 floats
  const float4* p = (const float4*)x + (size_t)i * 2;
  float4 a = p[0], b = p[1];
  float v[8] = {a.x, a.y, a.z, a.w, b.x, b.y, b.z, b.w};
  bf16x8 h, l;
#pragma unroll
  for (int j = 0; j < 8; ++j) {
    __bf16 hh = (__bf16)v[j];
    h[j] = hh;
    l[j] = (__bf16)(v[j] - (float)hh);
  }
  *(bf16x8*)(xh + (size_t)i * 8) = h;
  *(bf16x8*)(xl + (size_t)i * 8) = l;
}

// ------- weights: W[k][c] -> Wt[c][k] bf16 (hi/lo), out_proj -> Wot -------
__global__ __launch_bounds__(256) void k_conv_w(const float* __restrict__ wq,
                                                const float* __restrict__ wk,
                                                const float* __restrict__ wv,
                                                const float* __restrict__ op,
                                                __bf16* __restrict__ wt_h,
                                                __bf16* __restrict__ wt_l,
                                                __bf16* __restrict__ wot) {
  int idx = blockIdx.x * 256 + threadIdx.x;
  const int WT = 2304 * 768;
  if (idx < WT) {
    int c = idx / 768, kd = idx - c * 768;
    int which = c / 768, cc = c - which * 768;
    const float* w = (which == 0) ? wq : ((which == 1) ? wk : wv);
    float v = w[(size_t)kd * 768 + cc];
    __bf16 h = (__bf16)v;
    wt_h[idx] = h;
    wt_l[idx] = (__bf16)(v - (float)h);
  } else {
    int j = idx - WT;                       // < 589824
    int c = j / 768, kd = j - c * 768;
    wot[j] = (__bf16)op[(size_t)kd * 768 + c];
  }
}

// ---------------- fused QKV GEMM (split-bf16 for q,k cols) ----------------
// A: [8192][768] (hi/lo), Bt: [2304][768] (hi/lo). 128x128 tile, BK=32.
__global__ __launch_bounds__(256) void k_qkv_gemm(
    const __bf16* __restrict__ Ah, const __bf16* __restrict__ Al,
    const __bf16* __restrict__ Bh, const __bf16* __restrict__ Bl,
    __bf16* __restrict__ qh_o, __bf16* __restrict__ ql_o,
    __bf16* __restrict__ kh_o, __bf16* __restrict__ kl_o,
    __bf16* __restrict__ vT_o) {
  __shared__ __align__(16) __bf16 AsH[128 * 32];
  __shared__ __align__(16) __bf16 AsL[128 * 32];
  __shared__ __align__(16) __bf16 BsH[128 * 32];
  __shared__ __align__(16) __bf16 BsL[128 * 32];
  int t = threadIdx.x, lane = t & 63, wid = t >> 6;
  int l15 = lane & 15, lh = lane >> 4;
  int bid = blockIdx.x;
  int mt = bid & 63, nt = bid >> 6;         // 64 m-tiles, 18 n-tiles
  int m0 = mt * 128, n0 = nt * 128;
  int wr = wid >> 1, wc = wid & 1;          // 2x2 waves, 64x64 each
  bool split = (n0 < 1536);                 // q,k columns need hi/lo terms
  f32x4 acc[4][4];
#pragma unroll
  for (int i = 0; i < 4; ++i)
#pragma unroll
    for (int j = 0; j < 4; ++j) acc[i][j] = (f32x4){0.f, 0.f, 0.f, 0.f};

  int row0 = t >> 2,        kk0 = (t & 3) * 8;   // elems [t*8)
  int row1 = 64 + (t >> 2), kk1 = kk0;           // elems [(256+t)*8)
  char* lA0 = (char*)AsH + wid * 1024; char* lA1 = (char*)AsH + wid * 1024 + 4096;
  char* lAl0 = (char*)AsL + wid * 1024; char* lAl1 = (char*)AsL + wid * 1024 + 4096;
  char* lB0 = (char*)BsH + wid * 1024; char* lB1 = (char*)BsH + wid * 1024 + 4096;
  char* lBl0 = (char*)BsL + wid * 1024; char* lBl1 = (char*)BsL + wid * 1024 + 4096;

  for (int k0 = 0; k0 < 768; k0 += 32) {
    __syncthreads();
    size_t a0 = (size_t)(m0 + row0) * 768 + k0 + kk0;
    size_t a1 = (size_t)(m0 + row1) * 768 + k0 + kk1;
    size_t b0 = (size_t)(n0 + row0) * 768 + k0 + kk0;
    size_t b1 = (size_t)(n0 + row1) * 768 + k0 + kk1;
    GLL16(Ah + a0, lA0);  GLL16(Ah + a1, lA1);
    GLL16(Al + a0, lAl0); GLL16(Al + a1, lAl1);
    GLL16(Bh + b0, lB0);  GLL16(Bh + b1, lB1);
    GLL16(Bl + b0, lBl0); GLL16(Bl + b1, lBl1);
    asm volatile("s_waitcnt vmcnt(0)" ::: "memory");
    __syncthreads();

    bf16x8 af[4], alf[4], bf_[4], blf[4];
#pragma unroll
    for (int i = 0; i < 4; ++i) {
      int aoff = (wr * 64 + i * 16 + l15) * 32 + lh * 8;
      af[i]  = *(const bf16x8*)(AsH + aoff);
      alf[i] = *(const bf16x8*)(AsL + aoff);
      int boff = (wc * 64 + i * 16 + l15) * 32 + lh * 8;
      bf_[i] = *(const bf16x8*)(BsH + boff);
      blf[i] = *(const bf16x8*)(BsL + boff);
    }
#pragma unroll
    for (int i = 0; i < 4; ++i)
#pragma unroll
      for (int j = 0; j < 4; ++j) {
        acc[i][j] = MFMA16(af[i], bf_[j], acc[i][j]);
        if (split) {
          acc[i][j] = MFMA16(af[i], blf[j], acc[i][j]);
          acc[i][j] = MFMA16(alf[i], bf_[j], acc[i][j]);
        }
      }
  }
  // epilogue: C/D layout col=lane&15, row=(lane>>4)*4+r  [HW-verified]
#pragma unroll
  for (int j = 0; j < 4; ++j) {
    int c = n0 + wc * 64 + j * 16 + l15;
    int which = c / 768; int cc = c - which * 768;
    int hh = cc >> 6, d = cc & 63;
#pragma unroll
    for (int i = 0; i < 4; ++i)
#pragma unroll
      for (int r = 0; r < 4; ++r) {
        int m = m0 + wr * 64 + i * 16 + lh * 4 + r;
        int bb = m >> 11, n = m & 2047;
        float v = acc[i][j][r];
        if (which == 2) {
          // V stored transposed: [b,h,d,n]
          vT_o[((size_t)(bb * 12 + hh) * 64 + d) * 2048 + n] = (__bf16)v;
        } else {
          size_t o = ((size_t)(bb * 12 + hh) * 2048 + n) * 64 + d;
          __bf16 hi = (__bf16)v;
          __bf16 lo = (__bf16)(v - (float)hi);
          if (which == 0) { qh_o[o] = hi; ql_o[o] = lo; }
          else            { kh_o[o] = hi; kl_o[o] = lo; }
        }
      }
  }
}

// ---------------- causal flash attention ----------------
// grid = B*H*32 blocks; 4 waves/block, each wave owns 16 q-rows. No __syncthreads
// (waves have divergent trip counts). K/V read from global (L2-resident).
__global__ __launch_bounds__(256) void k_attn(
    const __bf16* __restrict__ Qh, const __bf16* __restrict__ Ql,
    const __bf16* __restrict__ Kh, const __bf16* __restrict__ Kl,
    const __bf16* __restrict__ Vt, __bf16* __restrict__ ctx) {
  __shared__ __align__(16) __bf16 plds[4][16 * 32];
  int t = threadIdx.x, lane = t & 63, wid = t >> 6;
  int l15 = lane & 15, lh = lane >> 4;
  int bid = blockIdx.x;
  int qt = bid & 31, bh = bid >> 5;         // bh = b*12+h
  int q0 = qt * 64 + wid * 16;
  size_t base = (size_t)bh * (2048 * 64);
  const __bf16* qhp = Qh + base;
  const __bf16* qlp = Ql + base;
  const __bf16* khp = Kh + base;
  const __bf16* klp = Kl + base;
  const __bf16* vtp = Vt + base;            // [64][2048] per (b,h)
  __bf16* pl = plds[wid];

  int qr = q0 + l15;
  bf16x8 qfh[2], qfl[2];
  qfh[0] = *(const bf16x8*)(qhp + (size_t)qr * 64 + lh * 8);
  qfh[1] = *(const bf16x8*)(qhp + (size_t)qr * 64 + 32 + lh * 8);
  qfl[0] = *(const bf16x8*)(qlp + (size_t)qr * 64 + lh * 8);
  qfl[1] = *(const bf16x8*)(qlp + (size_t)qr * 64 + 32 + lh * 8);

  f32x4 o[4];
#pragma unroll
  for (int d = 0; d < 4; ++d) o[d] = (f32x4){0.f, 0.f, 0.f, 0.f};
  float mrun[4], lrun[4];
#pragma unroll
  for (int r = 0; r < 4; ++r) { mrun[r] = -1e30f; lrun[r] = 0.f; }

  int nIter = (q0 + 47) >> 5;               // ceil((q0+16)/32)
  for (int it = 0; it < nIter; ++it) {
    int k0 = it << 5;
    f32x4 s0 = (f32x4){0.f, 0.f, 0.f, 0.f};
    f32x4 s1 = s0;
    {
      int kc = k0 + l15;
      const __bf16* kb  = khp + (size_t)kc * 64 + lh * 8;
      const __bf16* kbl = klp + (size_t)kc * 64 + lh * 8;
      bf16x8 h0 = *(const bf16x8*)kb,  h1 = *(const bf16x8*)(kb + 32);
      bf16x8 L0 = *(const bf16x8*)kbl, L1 = *(const bf16x8*)(kbl + 32);
      s0 = MFMA16(qfh[0], h0, s0); s0 = MFMA16(qfh[1], h1, s0);
      s0 = MFMA16(qfh[0], L0, s0); s0 = MFMA16(qfh[1], L1, s0);
      s0 = MFMA16(qfl[0], h0, s0); s0 = MFMA16(qfl[1], h1, s0);
    }
    {
      int kc = k0 + 16 + l15;
      const __bf16* kb  = khp + (size_t)kc * 64 + lh * 8;
      const __bf16* kbl = klp + (size_t)kc * 64 + lh * 8;
      bf16x8 h0 = *(const bf16x8*)kb,  h1 = *(const bf16x8*)(kb + 32);
      bf16x8 L0 = *(const bf16x8*)kbl, L1 = *(const bf16x8*)(kbl + 32);
      s1 = MFMA16(qfh[0], h0, s1); s1 = MFMA16(qfh[1], h1, s1);
      s1 = MFMA16(qfh[0], L0, s1); s1 = MFMA16(qfh[1], L1, s1);
      s1 = MFMA16(qfl[0], h0, s1); s1 = MFMA16(qfl[1], h1, s1);
    }
    float p0[4], p1[4], mx[4];
#pragma unroll
    for (int r = 0; r < 4; ++r) {
      int qg = q0 + lh * 4 + r;
      float a = s0[r] * 0.125f, b2 = s1[r] * 0.125f;
      if (k0 + l15 > qg)      a  = -1e30f;  // causal mask
      if (k0 + 16 + l15 > qg) b2 = -1e30f;
      p0[r] = a; p1[r] = b2;
      mx[r] = fmaxf(a, b2);
    }
#pragma unroll
    for (int off = 1; off < 16; off <<= 1)
#pragma unroll
      for (int r = 0; r < 4; ++r) mx[r] = fmaxf(mx[r], __shfl_xor(mx[r], off));
    float rs[4], alpha[4];
#pragma unroll
    for (int r = 0; r < 4; ++r) {
      float mn = fmaxf(mrun[r], mx[r]);
      alpha[r] = __expf(mrun[r] - mn);
      mrun[r] = mn;
      p0[r] = __expf(p0[r] - mn);
      p1[r] = __expf(p1[r] - mn);
      rs[r] = p0[r] + p1[r];
    }
#pragma unroll
    for (int off = 1; off < 16; off <<= 1)
#pragma unroll
      for (int r = 0; r < 4; ++r) rs[r] += __shfl_xor(rs[r], off);
#pragma unroll
    for (int r = 0; r < 4; ++r) lrun[r] = lrun[r] * alpha[r] + rs[r];
#pragma unroll
    for (int d = 0; d < 4; ++d)
#pragma unroll
      for (int r = 0; r < 4; ++r) o[d][r] *= alpha[r];
    // P (acc layout) -> LDS -> A-fragment layout (per-wave buffer, no barrier)
#pragma unroll
    for (int r = 0; r < 4; ++r) {
      pl[(lh * 4 + r) * 32 + l15]      = (__bf16)p0[r];
      pl[(lh * 4 + r) * 32 + 16 + l15] = (__bf16)p1[r];
    }
    asm volatile("" ::: "memory");
    bf16x8 pa = *(const bf16x8*)(pl + l15 * 32 + lh * 8);
    asm volatile("" ::: "memory");
#pragma unroll
    for (int d = 0; d < 4; ++d) {
      bf16x8 vf = *(const bf16x8*)(vtp + (size_t)(d * 16 + l15) * 2048 + k0 + lh * 8);
      o[d] = MFMA16(pa, vf, o[d]);
    }
  }
  int b = bh / 12, hh = bh - (bh / 12) * 12;
#pragma unroll
  for (int d = 0; d < 4; ++d)
#pragma unroll
    for (int r = 0; r < 4; ++r) {
      int qg = q0 + lh * 4 + r;
      float val = o[d][r] / lrun[r];
      ctx[((size_t)b * 2048 + qg) * 768 + hh * 64 + d * 16 + l15] = (__bf16)val;
    }
}

// ---------------- out projection: ctx(bf16) @ Wot -> fp32 ----------------
__global__ __launch_bounds__(256) void k_out_gemm(const __bf16* __restrict__ A,
                                                  const __bf16* __restrict__ Bt,
                                                  float* __restrict__ C) {
  __shared__ __align__(16) __bf16 As[128 * 32];
  __shared__ __align__(16) __bf16 Bs[128 * 32];
  int t = threadIdx.x, lane = t & 63, wid = t >> 6;
  int l15 = lane & 15, lh = lane >> 4;
  int bid = blockIdx.x;
  int mt = bid & 63, nt = bid >> 6;         // 64 x 6 tiles
  int m0 = mt * 128, n0 = nt * 128;
  int wr = wid >> 1, wc = wid & 1;
  f32x4 acc[4][4];
#pragma unroll
  for (int i = 0; i < 4; ++i)
#pragma unroll
    for (int j = 0; j < 4; ++j) acc[i][j] = (f32x4){0.f, 0.f, 0.f, 0.f};
  int row0 = t >> 2,        kk0 = (t & 3) * 8;
  int row1 = 64 + (t >> 2), kk1 = kk0;
  char* lA0 = (char*)As + wid * 1024; char* lA1 = (char*)As + wid * 1024 + 4096;
  char* lB0 = (char*)Bs + wid * 1024; char* lB1 = (char*)Bs + wid * 1024 + 4096;

  for (int k0 = 0; k0 < 768; k0 += 32) {
    __syncthreads();
    GLL16(A  + (size_t)(m0 + row0) * 768 + k0 + kk0, lA0);
    GLL16(A  + (size_t)(m0 + row1) * 768 + k0 + kk1, lA1);
    GLL16(Bt + (size_t)(n0 + row0) * 768 + k0 + kk0, lB0);
    GLL16(Bt + (size_t)(n0 + row1) * 768 + k0 + kk1, lB1);
    asm volatile("s_waitcnt vmcnt(0)" ::: "memory");
    __syncthreads();
    bf16x8 af[4], bf_[4];
#pragma unroll
    for (int i = 0; i < 4; ++i) {
      af[i]  = *(const bf16x8*)(As + (wr * 64 + i * 16 + l15) * 32 + lh * 8);
      bf_[i] = *(const bf16x8*)(Bs + (wc * 64 + i * 16 + l15) * 32 + lh * 8);
    }
#pragma unroll
    for (int i = 0; i < 4; ++i)
#pragma unroll
      for (int j = 0; j < 4; ++j) acc[i][j] = MFMA16(af[i], bf_[j], acc[i][j]);
  }
#pragma unroll
  for (int j = 0; j < 4; ++j) {
    int c = n0 + wc * 64 + j * 16 + l15;
#pragma unroll
    for (int i = 0; i < 4; ++i)
#pragma unroll
      for (int r = 0; r < 4; ++r) {
        int m = m0 + wr * 64 + i * 16 + lh * 4 + r;
        C[(size_t)m * 768 + c] = acc[i][j][r];
      }
  }
}

extern "C" void kernel_launch(void* const* d_in, const int* in_sizes, int n_in,
                              void* d_out, int out_size, void* d_ws, size_t ws_size,
                              hipStream_t stream) {
  const float* x  = (const float*)d_in[0];
  const float* wq = (const float*)d_in[1];
  const float* wk = (const float*)d_in[2];
  const float* wv = (const float*)d_in[3];
  const float* op = (const float*)d_in[4];
  float* out = (float*)d_out;

  char* ws = (char*)d_ws;
  const size_t SZ = (size_t)8192 * 768 * 2;          // 12.58 MB per bf16 tensor
  __bf16* xh   = (__bf16*)ws; ws += SZ;
  __bf16* xl   = (__bf16*)ws; ws += SZ;
  __bf16* wt_h = (__bf16*)ws; ws += (size_t)2304 * 768 * 2;
  __bf16* wt_l = (__bf16*)ws; ws += (size_t)2304 * 768 * 2;
  __bf16* wot  = (__bf16*)ws; ws += (size_t)768 * 768 * 2;
  __bf16* qh   = (__bf16*)ws; ws += SZ;
  __bf16* ql   = (__bf16*)ws; ws += SZ;
  __bf16* kh   = (__bf16*)ws; ws += SZ;
  __bf16* kl   = (__bf16*)ws; ws += SZ;
  __bf16* vT   = (__bf16*)ws; ws += SZ;
  __bf16* ctx  = (__bf16*)ws; ws += SZ;

  hipLaunchKernelGGL(k_conv_x, dim3(3072), dim3(256), 0, stream, x, xh, xl);
  hipLaunchKernelGGL(k_conv_w, dim3(9216), dim3(256), 0, stream,
                     wq, wk, wv, op, wt_h, wt_l, wot);
  hipLaunchKernelGGL(k_qkv_gemm, dim3(64 * 18), dim3(256), 0, stream,
                     xh, xl, wt_h, wt_l, qh, ql, kh, kl, vT);
  hipLaunchKernelGGL(k_attn, dim3(4 * 12 * 32), dim3(256), 0, stream,
                     qh, ql, kh, kl, vT, ctx);
  hipLaunchKernelGGL(k_out_gemm, dim3(64 * 6), dim3(256), 0, stream, ctx, wot, out);
}

// Round 2
// 347.305 us; speedup vs baseline: 2.0791x; 2.0791x over previous
//
#include <hip/hip_runtime.h>

typedef __bf16 bf16x8 __attribute__((ext_vector_type(8)));
typedef float  f32x4  __attribute__((ext_vector_type(4)));

#define MFMA16(a,b,c) __builtin_amdgcn_mfma_f32_16x16x32_bf16((a),(b),(c),0,0,0)

#define AS1(p) (const __attribute__((address_space(1))) void*)(p)
#define AS3(p) (__attribute__((address_space(3))) void*)(p)
#define GLL16(g, l) __builtin_amdgcn_global_load_lds(AS1(g), AS3(l), 16, 0, 0)

// B=4, N=2048, H=12, hd=64, D=768, M=B*N=8192

// ---------------- x -> (xh, xl) split bf16 ----------------
__global__ __launch_bounds__(256) void k_conv_x(const float* __restrict__ x,
                                                __bf16* __restrict__ xh,
                                                __bf16* __restrict__ xl) {
  int i = blockIdx.x * 256 + threadIdx.x;
  const float4* p = (const float4*)x + (size_t)i * 2;
  float4 a = p[0], b = p[1];
  float v[8] = {a.x, a.y, a.z, a.w, b.x, b.y, b.z, b.w};
  bf16x8 h, l;
#pragma unroll
  for (int j = 0; j < 8; ++j) {
    __bf16 hh = (__bf16)v[j];
    h[j] = hh;
    l[j] = (__bf16)(v[j] - (float)hh);
  }
  *(bf16x8*)(xh + (size_t)i * 8) = h;
  *(bf16x8*)(xl + (size_t)i * 8) = l;
}

// ------- weights: W[k][c] -> Wt[c][k] bf16 (hi/lo), out_proj -> Wot -------
__global__ __launch_bounds__(256) void k_conv_w(const float* __restrict__ wq,
                                                const float* __restrict__ wk,
                                                const float* __restrict__ wv,
                                                const float* __restrict__ op,
                                                __bf16* __restrict__ wt_h,
                                                __bf16* __restrict__ wt_l,
                                                __bf16* __restrict__ wot) {
  int idx = blockIdx.x * 256 + threadIdx.x;
  const int WT = 2304 * 768;
  if (idx < WT) {
    int c = idx / 768, kd = idx - c * 768;
    int which = c / 768, cc = c - which * 768;
    const float* w = (which == 0) ? wq : ((which == 1) ? wk : wv);
    float v = w[(size_t)kd * 768 + cc];
    __bf16 h = (__bf16)v;
    wt_h[idx] = h;
    wt_l[idx] = (__bf16)(v - (float)h);
  } else {
    int j = idx - WT;
    int c = j / 768, kd = j - c * 768;
    wot[j] = (__bf16)op[(size_t)kd * 768 + c];
  }
}

// ---------------- fused QKV GEMM (split-bf16 for q,k cols) ----------------
__global__ __launch_bounds__(256) void k_qkv_gemm(
    const __bf16* __restrict__ Ah, const __bf16* __restrict__ Al,
    const __bf16* __restrict__ Bh, const __bf16* __restrict__ Bl,
    __bf16* __restrict__ qh_o, __bf16* __restrict__ ql_o,
    __bf16* __restrict__ kh_o, __bf16* __restrict__ kl_o,
    __bf16* __restrict__ vT_o) {
  __shared__ __align__(16) __bf16 AsH[128 * 32];
  __shared__ __align__(16) __bf16 AsL[128 * 32];
  __shared__ __align__(16) __bf16 BsH[128 * 32];
  __shared__ __align__(16) __bf16 BsL[128 * 32];
  int t = threadIdx.x, lane = t & 63, wid = t >> 6;
  int l15 = lane & 15, lh = lane >> 4;
  int bid = blockIdx.x;
  int mt = bid & 63, nt = bid >> 6;
  int m0 = mt * 128, n0 = nt * 128;
  int wr = wid >> 1, wc = wid & 1;
  bool split = (n0 < 1536);
  f32x4 acc[4][4];
#pragma unroll
  for (int i = 0; i < 4; ++i)
#pragma unroll
    for (int j = 0; j < 4; ++j) acc[i][j] = (f32x4){0.f, 0.f, 0.f, 0.f};

  int row0 = t >> 2,        kk0 = (t & 3) * 8;
  int row1 = 64 + (t >> 2), kk1 = kk0;
  char* lA0 = (char*)AsH + wid * 1024; char* lA1 = (char*)AsH + wid * 1024 + 4096;
  char* lAl0 = (char*)AsL + wid * 1024; char* lAl1 = (char*)AsL + wid * 1024 + 4096;
  char* lB0 = (char*)BsH + wid * 1024; char* lB1 = (char*)BsH + wid * 1024 + 4096;
  char* lBl0 = (char*)BsL + wid * 1024; char* lBl1 = (char*)BsL + wid * 1024 + 4096;

  for (int k0 = 0; k0 < 768; k0 += 32) {
    __syncthreads();
    size_t a0 = (size_t)(m0 + row0) * 768 + k0 + kk0;
    size_t a1 = (size_t)(m0 + row1) * 768 + k0 + kk1;
    size_t b0 = (size_t)(n0 + row0) * 768 + k0 + kk0;
    size_t b1 = (size_t)(n0 + row1) * 768 + k0 + kk1;
    GLL16(Ah + a0, lA0);  GLL16(Ah + a1, lA1);
    GLL16(Al + a0, lAl0); GLL16(Al + a1, lAl1);
    GLL16(Bh + b0, lB0);  GLL16(Bh + b1, lB1);
    GLL16(Bl + b0, lBl0); GLL16(Bl + b1, lBl1);
    asm volatile("s_waitcnt vmcnt(0)" ::: "memory");
    __syncthreads();

    bf16x8 af[4], alf[4], bf_[4], blf[4];
#pragma unroll
    for (int i = 0; i < 4; ++i) {
      int aoff = (wr * 64 + i * 16 + l15) * 32 + lh * 8;
      af[i]  = *(const bf16x8*)(AsH + aoff);
      alf[i] = *(const bf16x8*)(AsL + aoff);
      int boff = (wc * 64 + i * 16 + l15) * 32 + lh * 8;
      bf_[i] = *(const bf16x8*)(BsH + boff);
      blf[i] = *(const bf16x8*)(BsL + boff);
    }
#pragma unroll
    for (int i = 0; i < 4; ++i)
#pragma unroll
      for (int j = 0; j < 4; ++j) {
        acc[i][j] = MFMA16(af[i], bf_[j], acc[i][j]);
        if (split) {
          acc[i][j] = MFMA16(af[i], blf[j], acc[i][j]);
          acc[i][j] = MFMA16(alf[i], bf_[j], acc[i][j]);
        }
      }
  }
#pragma unroll
  for (int j = 0; j < 4; ++j) {
    int c = n0 + wc * 64 + j * 16 + l15;
    int which = c / 768; int cc = c - which * 768;
    int hh = cc >> 6, d = cc & 63;
#pragma unroll
    for (int i = 0; i < 4; ++i)
#pragma unroll
      for (int r = 0; r < 4; ++r) {
        int m = m0 + wr * 64 + i * 16 + lh * 4 + r;
        int bb = m >> 11, n = m & 2047;
        float v = acc[i][j][r];
        if (which == 2) {
          vT_o[((size_t)(bb * 12 + hh) * 64 + d) * 2048 + n] = (__bf16)v;
        } else {
          size_t o = ((size_t)(bb * 12 + hh) * 2048 + n) * 64 + d;
          __bf16 hi = (__bf16)v;
          __bf16 lo = (__bf16)(v - (float)hi);
          if (which == 0) { qh_o[o] = hi; ql_o[o] = lo; }
          else            { kh_o[o] = hi; kl_o[o] = lo; }
        }
      }
  }
}

// ---------------- causal flash attention v2 ----------------
// 128 q-rows/block, 4 waves x 32 rows, 64 keys/iter. K(hi,lo)+V staged in LDS
// (shared by 4 waves) via global_load_lds with pre-swizzled global source
// (rule #21). Reversed qt dispatch for causal load balance.
__global__ __launch_bounds__(256) void k_attn(
    const __bf16* __restrict__ Qh, const __bf16* __restrict__ Ql,
    const __bf16* __restrict__ Kh, const __bf16* __restrict__ Kl,
    const __bf16* __restrict__ Vt, __bf16* __restrict__ ctx) {
  __shared__ __align__(16) __bf16 Ksh[64 * 64];
  __shared__ __align__(16) __bf16 Ksl[64 * 64];
  __shared__ __align__(16) __bf16 Vs[64 * 64];
  __shared__ __align__(16) __bf16 plds[4][32 * 64];
  int t = threadIdx.x, lane = t & 63, wid = t >> 6;
  int l15 = lane & 15, lh = lane >> 4;
  int bid = blockIdx.x;
  int bh = bid % 48;
  int qt = 15 - bid / 48;                    // heavy tiles dispatch first
  int qbase = qt * 128 + wid * 32;
  size_t base = (size_t)bh * (2048 * 64);
  const __bf16* qhp = Qh + base;
  const __bf16* qlp = Ql + base;
  __bf16* pl = plds[wid];

  // --- staging source addresses (inverse-swizzled global, linear LDS dest) ---
  int skey = t >> 3;                         // 0..31 (key row / V dim row)
  int sdb = t & 7;                           // 16B block within 128B row
  int ssw = (sdb ^ (skey & 7)) * 8;          // swizzled element offset
  const __bf16* ksrc_h = Kh + base + (size_t)skey * 64 + ssw;
  const __bf16* ksrc_l = Kl + base + (size_t)skey * 64 + ssw;
  const __bf16* vsrc = Vt + base + (size_t)skey * 2048 + ssw;
  char* dKh0 = (char*)Ksh + wid * 1024; char* dKh1 = dKh0 + 4096;
  char* dKl0 = (char*)Ksl + wid * 1024; char* dKl1 = dKl0 + 4096;
  char* dV0  = (char*)Vs  + wid * 1024; char* dV1  = dV0 + 4096;

  // --- Q fragments: 2 row-tiles x 2 K-chunks, hi and lo ---
  bf16x8 qfh[2][2], qfl[2][2];
#pragma unroll
  for (int i = 0; i < 2; ++i)
#pragma unroll
    for (int kk = 0; kk < 2; ++kk) {
      size_t o = (size_t)(qbase + i * 16 + l15) * 64 + kk * 32 + lh * 8;
      qfh[i][kk] = *(const bf16x8*)(qhp + o);
      qfl[i][kk] = *(const bf16x8*)(qlp + o);
    }

  f32x4 o[2][4];
#pragma unroll
  for (int i = 0; i < 2; ++i)
#pragma unroll
    for (int d = 0; d < 4; ++d) o[i][d] = (f32x4){0.f, 0.f, 0.f, 0.f};
  float mrun[2][4], lrun[2][4];
#pragma unroll
  for (int i = 0; i < 2; ++i)
#pragma unroll
    for (int r = 0; r < 4; ++r) { mrun[i][r] = -1e30f; lrun[i][r] = 0.f; }

  int nIter = 2 * qt + 2;                    // covers keys 0 .. (qt+1)*128-1
  for (int it = 0; it < nIter; ++it) {
    int k0 = it * 64;
    __syncthreads();
    GLL16(ksrc_h + (size_t)k0 * 64, dKh0);
    GLL16(ksrc_h + (size_t)k0 * 64 + 2048, dKh1);
    GLL16(ksrc_l + (size_t)k0 * 64, dKl0);
    GLL16(ksrc_l + (size_t)k0 * 64 + 2048, dKl1);
    GLL16(vsrc + k0, dV0);
    GLL16(vsrc + k0 + 32 * 2048, dV1);
    asm volatile("s_waitcnt vmcnt(0)" ::: "memory");
    __syncthreads();

    // --- QK^T (3-term split) ---
    f32x4 s[2][4];
#pragma unroll
    for (int i = 0; i < 2; ++i)
#pragma unroll
      for (int j = 0; j < 4; ++j) s[i][j] = (f32x4){0.f, 0.f, 0.f, 0.f};
#pragma unroll
    for (int j = 0; j < 4; ++j) {
      int kc = j * 16 + l15;
#pragma unroll
      for (int kk = 0; kk < 2; ++kk) {
        int sw = ((kk * 4 + lh) ^ (kc & 7)) << 4;
        bf16x8 kfh = *(const bf16x8*)((char*)Ksh + kc * 128 + sw);
        bf16x8 kfl = *(const bf16x8*)((char*)Ksl + kc * 128 + sw);
        s[0][j] = MFMA16(qfh[0][kk], kfh, s[0][j]);
        s[0][j] = MFMA16(qfh[0][kk], kfl, s[0][j]);
        s[0][j] = MFMA16(qfl[0][kk], kfh, s[0][j]);
        s[1][j] = MFMA16(qfh[1][kk], kfh, s[1][j]);
        s[1][j] = MFMA16(qfh[1][kk], kfl, s[1][j]);
        s[1][j] = MFMA16(qfl[1][kk], kfh, s[1][j]);
      }
    }

    // --- mask + scale + online softmax ---
    float p[2][4][4], mx[2][4];
#pragma unroll
    for (int i = 0; i < 2; ++i) {
#pragma unroll
      for (int r = 0; r < 4; ++r) {
        int qg = qbase + i * 16 + lh * 4 + r;
        float m0v = -1e30f;
#pragma unroll
        for (int j = 0; j < 4; ++j) {
          float v = s[i][j][r] * 0.125f;
          if (k0 + j * 16 + l15 > qg) v = -1e30f;
          p[i][j][r] = v;
          m0v = fmaxf(m0v, v);
        }
        mx[i][r] = m0v;
      }
    }
#pragma unroll
    for (int off = 1; off < 16; off <<= 1)
#pragma unroll
      for (int i = 0; i < 2; ++i)
#pragma unroll
        for (int r = 0; r < 4; ++r) mx[i][r] = fmaxf(mx[i][r], __shfl_xor(mx[i][r], off));
    float rs[2][4], alpha[2][4];
#pragma unroll
    for (int i = 0; i < 2; ++i)
#pragma unroll
      for (int r = 0; r < 4; ++r) {
        float mn = fmaxf(mrun[i][r], mx[i][r]);
        alpha[i][r] = __expf(mrun[i][r] - mn);
        mrun[i][r] = mn;
        float acc = 0.f;
#pragma unroll
        for (int j = 0; j < 4; ++j) {
          float e = __expf(p[i][j][r] - mn);
          p[i][j][r] = e;
          acc += e;
        }
        rs[i][r] = acc;
      }
#pragma unroll
    for (int off = 1; off < 16; off <<= 1)
#pragma unroll
      for (int i = 0; i < 2; ++i)
#pragma unroll
        for (int r = 0; r < 4; ++r) rs[i][r] += __shfl_xor(rs[i][r], off);
#pragma unroll
    for (int i = 0; i < 2; ++i)
#pragma unroll
      for (int r = 0; r < 4; ++r) lrun[i][r] = lrun[i][r] * alpha[i][r] + rs[i][r];
#pragma unroll
    for (int i = 0; i < 2; ++i)
#pragma unroll
      for (int d = 0; d < 4; ++d)
#pragma unroll
        for (int r = 0; r < 4; ++r) o[i][d][r] *= alpha[i][r];

    // --- P -> LDS (acc layout -> A-frag layout), XOR-swizzled both sides ---
#pragma unroll
    for (int i = 0; i < 2; ++i)
#pragma unroll
      for (int j = 0; j < 4; ++j)
#pragma unroll
        for (int r = 0; r < 4; ++r) {
          int row = i * 16 + lh * 4 + r;
          int byteoff = (row * 128 + (j * 16 + l15) * 2) ^ ((row & 7) << 4);
          *(__bf16*)((char*)pl + byteoff) = (__bf16)p[i][j][r];
        }
    asm volatile("" ::: "memory");
    bf16x8 pa[2][2];
#pragma unroll
    for (int i = 0; i < 2; ++i)
#pragma unroll
      for (int kk = 0; kk < 2; ++kk) {
        int row = i * 16 + l15;
        int byteoff = (row * 128 + kk * 64 + lh * 16) ^ ((row & 7) << 4);
        pa[i][kk] = *(const bf16x8*)((char*)pl + byteoff);
      }
    asm volatile("" ::: "memory");

    // --- PV ---
#pragma unroll
    for (int dt = 0; dt < 4; ++dt) {
      int dr = dt * 16 + l15;
#pragma unroll
      for (int kk = 0; kk < 2; ++kk) {
        int sw = ((kk * 4 + lh) ^ (dr & 7)) << 4;
        bf16x8 vf = *(const bf16x8*)((char*)Vs + dr * 128 + sw);
        o[0][dt] = MFMA16(pa[0][kk], vf, o[0][dt]);
        o[1][dt] = MFMA16(pa[1][kk], vf, o[1][dt]);
      }
    }
  }

  int b = bh / 12, hh = bh - (bh / 12) * 12;
#pragma unroll
  for (int i = 0; i < 2; ++i)
#pragma unroll
    for (int dt = 0; dt < 4; ++dt)
#pragma unroll
      for (int r = 0; r < 4; ++r) {
        int qg = qbase + i * 16 + lh * 4 + r;
        float val = o[i][dt][r] / lrun[i][r];
        ctx[((size_t)b * 2048 + qg) * 768 + hh * 64 + dt * 16 + l15] = (__bf16)val;
      }
}

// ---------------- out projection: ctx(bf16) @ Wot -> fp32 ----------------
__global__ __launch_bounds__(256) void k_out_gemm(const __bf16* __restrict__ A,
                                                  const __bf16* __restrict__ Bt,
                                                  float* __restrict__ C) {
  __shared__ __align__(16) __bf16 As[128 * 32];
  __shared__ __align__(16) __bf16 Bs[128 * 32];
  int t = threadIdx.x, lane = t & 63, wid = t >> 6;
  int l15 = lane & 15, lh = lane >> 4;
  int bid = blockIdx.x;
  int mt = bid & 63, nt = bid >> 6;
  int m0 = mt * 128, n0 = nt * 128;
  int wr = wid >> 1, wc = wid & 1;
  f32x4 acc[4][4];
#pragma unroll
  for (int i = 0; i < 4; ++i)
#pragma unroll
    for (int j = 0; j < 4; ++j) acc[i][j] = (f32x4){0.f, 0.f, 0.f, 0.f};
  int row0 = t >> 2,        kk0 = (t & 3) * 8;
  int row1 = 64 + (t >> 2), kk1 = kk0;
  char* lA0 = (char*)As + wid * 1024; char* lA1 = (char*)As + wid * 1024 + 4096;
  char* lB0 = (char*)Bs + wid * 1024; char* lB1 = (char*)Bs + wid * 1024 + 4096;

  for (int k0 = 0; k0 < 768; k0 += 32) {
    __syncthreads();
    GLL16(A  + (size_t)(m0 + row0) * 768 + k0 + kk0, lA0);
    GLL16(A  + (size_t)(m0 + row1) * 768 + k0 + kk1, lA1);
    GLL16(Bt + (size_t)(n0 + row0) * 768 + k0 + kk0, lB0);
    GLL16(Bt + (size_t)(n0 + row1) * 768 + k0 + kk1, lB1);
    asm volatile("s_waitcnt vmcnt(0)" ::: "memory");
    __syncthreads();
    bf16x8 af[4], bf_[4];
#pragma unroll
    for (int i = 0; i < 4; ++i) {
      af[i]  = *(const bf16x8*)(As + (wr * 64 + i * 16 + l15) * 32 + lh * 8);
      bf_[i] = *(const bf16x8*)(Bs + (wc * 64 + i * 16 + l15) * 32 + lh * 8);
    }
#pragma unroll
    for (int i = 0; i < 4; ++i)
#pragma unroll
      for (int j = 0; j < 4; ++j) acc[i][j] = MFMA16(af[i], bf_[j], acc[i][j]);
  }
#pragma unroll
  for (int j = 0; j < 4; ++j) {
    int c = n0 + wc * 64 + j * 16 + l15;
#pragma unroll
    for (int i = 0; i < 4; ++i)
#pragma unroll
      for (int r = 0; r < 4; ++r) {
        int m = m0 + wr * 64 + i * 16 + lh * 4 + r;
        C[(size_t)m * 768 + c] = acc[i][j][r];
      }
  }
}

extern "C" void kernel_launch(void* const* d_in, const int* in_sizes, int n_in,
                              void* d_out, int out_size, void* d_ws, size_t ws_size,
                              hipStream_t stream) {
  const float* x  = (const float*)d_in[0];
  const float* wq = (const float*)d_in[1];
  const float* wk = (const float*)d_in[2];
  const float* wv = (const float*)d_in[3];
  const float* op = (const float*)d_in[4];
  float* out = (float*)d_out;

  char* ws = (char*)d_ws;
  const size_t SZ = (size_t)8192 * 768 * 2;
  __bf16* xh   = (__bf16*)ws; ws += SZ;
  __bf16* xl   = (__bf16*)ws; ws += SZ;
  __bf16* wt_h = (__bf16*)ws; ws += (size_t)2304 * 768 * 2;
  __bf16* wt_l = (__bf16*)ws; ws += (size_t)2304 * 768 * 2;
  __bf16* wot  = (__bf16*)ws; ws += (size_t)768 * 768 * 2;
  __bf16* qh   = (__bf16*)ws; ws += SZ;
  __bf16* ql   = (__bf16*)ws; ws += SZ;
  __bf16* kh   = (__bf16*)ws; ws += SZ;
  __bf16* kl   = (__bf16*)ws; ws += SZ;
  __bf16* vT   = (__bf16*)ws; ws += SZ;
  __bf16* ctx  = (__bf16*)ws; ws += SZ;

  hipLaunchKernelGGL(k_conv_x, dim3(3072), dim3(256), 0, stream, x, xh, xl);
  hipLaunchKernelGGL(k_conv_w, dim3(9216), dim3(256), 0, stream,
                     wq, wk, wv, op, wt_h, wt_l, wot);
  hipLaunchKernelGGL(k_qkv_gemm, dim3(64 * 18), dim3(256), 0, stream,
                     xh, xl, wt_h, wt_l, qh, ql, kh, kl, vT);
  hipLaunchKernelGGL(k_attn, dim3(48 * 16), dim3(256), 0, stream,
                     qh, ql, kh, kl, vT, ctx);
  hipLaunchKernelGGL(k_out_gemm, dim3(64 * 6), dim3(256), 0, stream, ctx, wot, out);
}

// Round 3
// 288.177 us; speedup vs baseline: 2.5057x; 1.2052x over previous
//
#include <hip/hip_runtime.h>

typedef __bf16 bf16x8 __attribute__((ext_vector_type(8)));
typedef __bf16 bf16x4 __attribute__((ext_vector_type(4)));
typedef float  f32x4  __attribute__((ext_vector_type(4)));

#define MFMA16(a,b,c) __builtin_amdgcn_mfma_f32_16x16x32_bf16((a),(b),(c),0,0,0)

#define AS1(p) (const __attribute__((address_space(1))) void*)(p)
#define AS3(p) (__attribute__((address_space(3))) void*)(p)
#define GLL16(g, l) __builtin_amdgcn_global_load_lds(AS1(g), AS3(l), 16, 0, 0)

__device__ __forceinline__ float fexp2(float x) {
  float r; asm("v_exp_f32 %0, %1" : "=v"(r) : "v"(x)); return r;
}

// B=4, N=2048, H=12, hd=64, D=768, M=B*N=8192
// Q is stored pre-scaled by log2(e)/8 so softmax uses exp2 directly.
#define QSCALE 0.18033688011112042f

// ---------------- x -> (xh, xl) split bf16 ----------------
__global__ __launch_bounds__(256) void k_conv_x(const float* __restrict__ x,
                                                __bf16* __restrict__ xh,
                                                __bf16* __restrict__ xl) {
  int i = blockIdx.x * 256 + threadIdx.x;
  const float4* p = (const float4*)x + (size_t)i * 2;
  float4 a = p[0], b = p[1];
  float v[8] = {a.x, a.y, a.z, a.w, b.x, b.y, b.z, b.w};
  bf16x8 h, l;
#pragma unroll
  for (int j = 0; j < 8; ++j) {
    __bf16 hh = (__bf16)v[j];
    h[j] = hh;
    l[j] = (__bf16)(v[j] - (float)hh);
  }
  *(bf16x8*)(xh + (size_t)i * 8) = h;
  *(bf16x8*)(xl + (size_t)i * 8) = l;
}

// ------- weights: W[k][c] -> Wt[c][k] bf16 (hi/lo), LDS-tiled transpose -------
// grid: 4 matrices x 24x24 tiles of 32x32; block 256 = (32,8)
__global__ __launch_bounds__(256) void k_conv_w(const float* __restrict__ wq,
                                                const float* __restrict__ wk,
                                                const float* __restrict__ wv,
                                                const float* __restrict__ op,
                                                __bf16* __restrict__ wt_h,
                                                __bf16* __restrict__ wt_l,
                                                __bf16* __restrict__ wot) {
  __shared__ float tile[32][33];
  int bid = blockIdx.x;
  int m = bid / 576, rem = bid % 576;
  int tr = rem / 24, tc = rem % 24;
  const float* src = (m == 0) ? wq : (m == 1) ? wk : (m == 2) ? wv : op;
  int tx = threadIdx.x & 31, ty = threadIdx.x >> 5;
  int r0 = tr * 32, c0 = tc * 32;
#pragma unroll
  for (int j = 0; j < 4; ++j)
    tile[ty + j * 8][tx] = src[(size_t)(r0 + ty + j * 8) * 768 + c0 + tx];
  __syncthreads();
#pragma unroll
  for (int j = 0; j < 4; ++j) {
    float v = tile[tx][ty + j * 8];
    size_t o = (size_t)(c0 + ty + j * 8) * 768 + r0 + tx;
    if (m < 3) {
      size_t oo = (size_t)m * (768 * 768) + o;
      __bf16 h = (__bf16)v;
      wt_h[oo] = h;
      wt_l[oo] = (__bf16)(v - (float)h);
    } else {
      wot[o] = (__bf16)v;
    }
  }
}

// ---------------- fused QKV GEMM (split-bf16 for q,k cols) ----------------
__global__ __launch_bounds__(256) void k_qkv_gemm(
    const __bf16* __restrict__ Ah, const __bf16* __restrict__ Al,
    const __bf16* __restrict__ Bh, const __bf16* __restrict__ Bl,
    __bf16* __restrict__ qh_o, __bf16* __restrict__ ql_o,
    __bf16* __restrict__ kh_o, __bf16* __restrict__ kl_o,
    __bf16* __restrict__ vT_o) {
  __shared__ __align__(16) __bf16 AsH[128 * 32];
  __shared__ __align__(16) __bf16 AsL[128 * 32];
  __shared__ __align__(16) __bf16 BsH[128 * 32];
  __shared__ __align__(16) __bf16 BsL[128 * 32];
  int t = threadIdx.x, lane = t & 63, wid = t >> 6;
  int l15 = lane & 15, lh = lane >> 4;
  int bid = blockIdx.x;
  int mt = bid & 63, nt = bid >> 6;
  int m0 = mt * 128, n0 = nt * 128;
  int wr = wid >> 1, wc = wid & 1;
  bool split = (n0 < 1536);
  f32x4 acc[4][4];
#pragma unroll
  for (int i = 0; i < 4; ++i)
#pragma unroll
    for (int j = 0; j < 4; ++j) acc[i][j] = (f32x4){0.f, 0.f, 0.f, 0.f};

  int row0 = t >> 2,        kk0 = (t & 3) * 8;
  int row1 = 64 + (t >> 2), kk1 = kk0;
  char* lA0 = (char*)AsH + wid * 1024; char* lA1 = (char*)AsH + wid * 1024 + 4096;
  char* lAl0 = (char*)AsL + wid * 1024; char* lAl1 = (char*)AsL + wid * 1024 + 4096;
  char* lB0 = (char*)BsH + wid * 1024; char* lB1 = (char*)BsH + wid * 1024 + 4096;
  char* lBl0 = (char*)BsL + wid * 1024; char* lBl1 = (char*)BsL + wid * 1024 + 4096;

  for (int k0 = 0; k0 < 768; k0 += 32) {
    __syncthreads();
    size_t a0 = (size_t)(m0 + row0) * 768 + k0 + kk0;
    size_t a1 = (size_t)(m0 + row1) * 768 + k0 + kk1;
    size_t b0 = (size_t)(n0 + row0) * 768 + k0 + kk0;
    size_t b1 = (size_t)(n0 + row1) * 768 + k0 + kk1;
    GLL16(Ah + a0, lA0);  GLL16(Ah + a1, lA1);
    GLL16(Al + a0, lAl0); GLL16(Al + a1, lAl1);
    GLL16(Bh + b0, lB0);  GLL16(Bh + b1, lB1);
    GLL16(Bl + b0, lBl0); GLL16(Bl + b1, lBl1);
    asm volatile("s_waitcnt vmcnt(0)" ::: "memory");
    __syncthreads();

    bf16x8 af[4], alf[4], bf_[4], blf[4];
#pragma unroll
    for (int i = 0; i < 4; ++i) {
      int aoff = (wr * 64 + i * 16 + l15) * 32 + lh * 8;
      af[i]  = *(const bf16x8*)(AsH + aoff);
      alf[i] = *(const bf16x8*)(AsL + aoff);
      int boff = (wc * 64 + i * 16 + l15) * 32 + lh * 8;
      bf_[i] = *(const bf16x8*)(BsH + boff);
      blf[i] = *(const bf16x8*)(BsL + boff);
    }
#pragma unroll
    for (int i = 0; i < 4; ++i)
#pragma unroll
      for (int j = 0; j < 4; ++j) {
        acc[i][j] = MFMA16(af[i], bf_[j], acc[i][j]);
        if (split) {
          acc[i][j] = MFMA16(af[i], blf[j], acc[i][j]);
          acc[i][j] = MFMA16(alf[i], bf_[j], acc[i][j]);
        }
      }
  }
#pragma unroll
  for (int j = 0; j < 4; ++j) {
    int c = n0 + wc * 64 + j * 16 + l15;
    int which = c / 768; int cc = c - which * 768;
    int hh = cc >> 6, d = cc & 63;
#pragma unroll
    for (int i = 0; i < 4; ++i)
#pragma unroll
      for (int r = 0; r < 4; ++r) {
        int m = m0 + wr * 64 + i * 16 + lh * 4 + r;
        int bb = m >> 11, n = m & 2047;
        float v = acc[i][j][r];
        if (which == 2) {
          vT_o[((size_t)(bb * 12 + hh) * 64 + d) * 2048 + n] = (__bf16)v;
        } else {
          size_t o = ((size_t)(bb * 12 + hh) * 2048 + n) * 64 + d;
          if (which == 0) {
            float vs = v * QSCALE;            // fold 1/sqrt(hd) and log2(e)
            __bf16 hi = (__bf16)vs;
            qh_o[o] = hi; ql_o[o] = (__bf16)(vs - (float)hi);
          } else {
            __bf16 hi = (__bf16)v;
            kh_o[o] = hi; kl_o[o] = (__bf16)(v - (float)hi);
          }
        }
      }
  }
}

// ---------------- causal flash attention v3 (swapped QK^T) ----------------
// S^T = mfma(K,Q): lane owns one q-row's S-values -> in-lane softmax reduce.
// Masks only on diagonal iters (wave-uniform branch); exp2-domain logits.
__global__ __launch_bounds__(256) void k_attn(
    const __bf16* __restrict__ Qh, const __bf16* __restrict__ Ql,
    const __bf16* __restrict__ Kh, const __bf16* __restrict__ Kl,
    const __bf16* __restrict__ Vt, __bf16* __restrict__ ctx) {
  __shared__ __align__(16) __bf16 Ksh[64 * 64];
  __shared__ __align__(16) __bf16 Ksl[64 * 64];
  __shared__ __align__(16) __bf16 Vs[64 * 64];
  __shared__ __align__(16) __bf16 Pt[4][32 * 64];   // per-wave P^T / ctx staging
  int t = threadIdx.x, lane = t & 63, wid = t >> 6;
  int l15 = lane & 15, lh = lane >> 4;
  int bid = blockIdx.x;
  int bh = bid % 48;
  int qt = 15 - bid / 48;                    // heavy tiles dispatch first
  int qbase = qt * 128 + wid * 32;
  size_t base = (size_t)bh * (2048 * 64);
  char* ptw = (char*)Pt[wid];

  // staging: inverse-swizzled global source, linear LDS dest (rule #21)
  int skey = t >> 3, sdb = t & 7;
  int ssw = (sdb ^ (skey & 7)) * 8;
  const __bf16* ksrc_h = Kh + base + (size_t)skey * 64 + ssw;
  const __bf16* ksrc_l = Kl + base + (size_t)skey * 64 + ssw;
  const __bf16* vsrc = Vt + base + (size_t)skey * 2048 + ssw;
  char* dKh0 = (char*)Ksh + wid * 1024; char* dKh1 = dKh0 + 4096;
  char* dKl0 = (char*)Ksl + wid * 1024; char* dKl1 = dKl0 + 4096;
  char* dV0  = (char*)Vs  + wid * 1024; char* dV1  = dV0 + 4096;

  // Q fragments (pre-scaled by QSCALE in qkv epilogue)
  bf16x8 qfh[2][2], qfl[2][2];
#pragma unroll
  for (int i = 0; i < 2; ++i)
#pragma unroll
    for (int kk = 0; kk < 2; ++kk) {
      size_t o = (size_t)(qbase + i * 16 + l15) * 64 + kk * 32 + lh * 8;
      qfh[i][kk] = *(const bf16x8*)(Qh + base + o);
      qfl[i][kk] = *(const bf16x8*)(Ql + base + o);
    }

  f32x4 o[2][4];                              // ctx^T: row d, col q(=l15,+16i)
#pragma unroll
  for (int i = 0; i < 2; ++i)
#pragma unroll
    for (int d = 0; d < 4; ++d) o[i][d] = (f32x4){0.f, 0.f, 0.f, 0.f};
  float mrun[2] = {-1e30f, -1e30f}, lrun[2] = {0.f, 0.f};

  int nIter = 2 * qt + 2;
  for (int it = 0; it < nIter; ++it) {
    int k0 = it * 64;
    __syncthreads();
    GLL16(ksrc_h + (size_t)k0 * 64, dKh0);
    GLL16(ksrc_h + (size_t)k0 * 64 + 2048, dKh1);
    GLL16(ksrc_l + (size_t)k0 * 64, dKl0);
    GLL16(ksrc_l + (size_t)k0 * 64 + 2048, dKl1);
    GLL16(vsrc + k0, dV0);
    GLL16(vsrc + k0 + 32 * 2048, dV1);
    asm volatile("s_waitcnt vmcnt(0)" ::: "memory");
    __syncthreads();

    if (k0 > qbase + 31) continue;           // fully-masked for this wave

    // --- S^T = K (hi+lo) x Q (hi+lo), 3-term split ---
    f32x4 s[4][2];                           // [key-tile j][q-tile i]
#pragma unroll
    for (int j = 0; j < 4; ++j)
#pragma unroll
      for (int i = 0; i < 2; ++i) s[j][i] = (f32x4){0.f, 0.f, 0.f, 0.f};
#pragma unroll
    for (int j = 0; j < 4; ++j) {
      int kr = j * 16 + l15;                 // A row = key
#pragma unroll
      for (int kk = 0; kk < 2; ++kk) {
        int sw = ((kk * 4 + lh) ^ (kr & 7)) << 4;
        bf16x8 kfh = *(const bf16x8*)((char*)Ksh + kr * 128 + sw);
        bf16x8 kfl = *(const bf16x8*)((char*)Ksl + kr * 128 + sw);
        s[j][0] = MFMA16(kfh, qfh[0][kk], s[j][0]);
        s[j][0] = MFMA16(kfl, qfh[0][kk], s[j][0]);
        s[j][0] = MFMA16(kfh, qfl[0][kk], s[j][0]);
        s[j][1] = MFMA16(kfh, qfh[1][kk], s[j][1]);
        s[j][1] = MFMA16(kfl, qfh[1][kk], s[j][1]);
        s[j][1] = MFMA16(kfh, qfl[1][kk], s[j][1]);
      }
    }

    if (k0 + 63 > qbase) {                   // diagonal iter: apply causal mask
#pragma unroll
      for (int j = 0; j < 4; ++j)
#pragma unroll
        for (int i = 0; i < 2; ++i)
#pragma unroll
          for (int r = 0; r < 4; ++r) {
            int key = k0 + j * 16 + lh * 4 + r;
            int qg = qbase + i * 16 + l15;
            if (key > qg) s[j][i][r] = -1e30f;
          }
    }

    // --- online softmax: in-lane tree + 2 shuffles per q-tile ---
#pragma unroll
    for (int i = 0; i < 2; ++i) {
      float m01 = fmaxf(fmaxf(s[0][i][0], s[0][i][1]), fmaxf(s[0][i][2], s[0][i][3]));
      float m23 = fmaxf(fmaxf(s[1][i][0], s[1][i][1]), fmaxf(s[1][i][2], s[1][i][3]));
      float m45 = fmaxf(fmaxf(s[2][i][0], s[2][i][1]), fmaxf(s[2][i][2], s[2][i][3]));
      float m67 = fmaxf(fmaxf(s[3][i][0], s[3][i][1]), fmaxf(s[3][i][2], s[3][i][3]));
      float mx = fmaxf(fmaxf(m01, m23), fmaxf(m45, m67));
      mx = fmaxf(mx, __shfl_xor(mx, 16));
      mx = fmaxf(mx, __shfl_xor(mx, 32));
      float mn = fmaxf(mrun[i], mx);
      float alpha = fexp2(mrun[i] - mn);
      mrun[i] = mn;
      float rsum = 0.f;
#pragma unroll
      for (int j = 0; j < 4; ++j)
#pragma unroll
        for (int r = 0; r < 4; ++r) {
          float e = fexp2(s[j][i][r] - mn);
          s[j][i][r] = e;
          rsum += e;
        }
      rsum += __shfl_xor(rsum, 16);
      rsum += __shfl_xor(rsum, 32);
      lrun[i] = lrun[i] * alpha + rsum;
#pragma unroll
      for (int d = 0; d < 4; ++d) o[i][d] *= alpha;
      // P^T -> LDS, packed 4 contiguous keys per write, XOR-swizzled
#pragma unroll
      for (int j = 0; j < 4; ++j) {
        bf16x4 pk = { (__bf16)s[j][i][0], (__bf16)s[j][i][1],
                      (__bf16)s[j][i][2], (__bf16)s[j][i][3] };
        int row = 16 * i + l15;
        int boff = (row * 128 + j * 32 + lh * 8) ^ ((l15 & 7) << 4);
        *(bf16x4*)(ptw + boff) = pk;
      }
    }
    asm volatile("" ::: "memory");
    bf16x8 pa[2][2];                         // B-frag: col=q, k=keys
#pragma unroll
    for (int i = 0; i < 2; ++i)
#pragma unroll
      for (int kk = 0; kk < 2; ++kk) {
        int row = 16 * i + l15;
        int boff = (row * 128 + kk * 64 + lh * 16) ^ ((l15 & 7) << 4);
        pa[i][kk] = *(const bf16x8*)(ptw + boff);
      }
    asm volatile("" ::: "memory");

    // --- ctx^T += V^T x P^T ---
#pragma unroll
    for (int dt = 0; dt < 4; ++dt) {
      int dr = dt * 16 + l15;
#pragma unroll
      for (int kk = 0; kk < 2; ++kk) {
        int sw = ((kk * 4 + lh) ^ (dr & 7)) << 4;
        bf16x8 vf = *(const bf16x8*)((char*)Vs + dr * 128 + sw);
        o[0][dt] = MFMA16(vf, pa[0][kk], o[0][dt]);
        o[1][dt] = MFMA16(vf, pa[1][kk], o[1][dt]);
      }
    }
  }

  // --- epilogue: normalize, transpose via per-wave LDS, coalesced store ---
  int b = bh / 12, hh = bh - (bh / 12) * 12;
  float inv[2] = {1.f / lrun[0], 1.f / lrun[1]};
#pragma unroll
  for (int i = 0; i < 2; ++i)
#pragma unroll
    for (int dt = 0; dt < 4; ++dt) {
      bf16x4 cw = { (__bf16)(o[i][dt][0] * inv[i]), (__bf16)(o[i][dt][1] * inv[i]),
                    (__bf16)(o[i][dt][2] * inv[i]), (__bf16)(o[i][dt][3] * inv[i]) };
      int row = 16 * i + l15;
      int boff = (row * 128 + dt * 32 + lh * 8) ^ ((l15 & 7) << 4);
      *(bf16x4*)(ptw + boff) = cw;
    }
  asm volatile("" ::: "memory");
  int lr = lane >> 1, hc = lane & 1;
#pragma unroll
  for (int q16 = 0; q16 < 4; ++q16) {
    int boff = (lr * 128 + hc * 64 + q16 * 16) ^ ((lr & 7) << 4);
    bf16x8 vv = *(const bf16x8*)(ptw + boff);
    *(bf16x8*)(ctx + ((size_t)b * 2048 + qbase + lr) * 768 + hh * 64 + hc * 32 + q16 * 8) = vv;
  }
}

// ---------------- out projection: ctx(bf16) @ Wot -> fp32 ----------------
__global__ __launch_bounds__(256) void k_out_gemm(const __bf16* __restrict__ A,
                                                  const __bf16* __restrict__ Bt,
                                                  float* __restrict__ C) {
  __shared__ __align__(16) __bf16 As[128 * 32];
  __shared__ __align__(16) __bf16 Bs[128 * 32];
  int t = threadIdx.x, lane = t & 63, wid = t >> 6;
  int l15 = lane & 15, lh = lane >> 4;
  int bid = blockIdx.x;
  int mt = bid & 63, nt = bid >> 6;
  int m0 = mt * 128, n0 = nt * 128;
  int wr = wid >> 1, wc = wid & 1;
  f32x4 acc[4][4];
#pragma unroll
  for (int i = 0; i < 4; ++i)
#pragma unroll
    for (int j = 0; j < 4; ++j) acc[i][j] = (f32x4){0.f, 0.f, 0.f, 0.f};
  int row0 = t >> 2,        kk0 = (t & 3) * 8;
  int row1 = 64 + (t >> 2), kk1 = kk0;
  char* lA0 = (char*)As + wid * 1024; char* lA1 = (char*)As + wid * 1024 + 4096;
  char* lB0 = (char*)Bs + wid * 1024; char* lB1 = (char*)Bs + wid * 1024 + 4096;

  for (int k0 = 0; k0 < 768; k0 += 32) {
    __syncthreads();
    GLL16(A  + (size_t)(m0 + row0) * 768 + k0 + kk0, lA0);
    GLL16(A  + (size_t)(m0 + row1) * 768 + k0 + kk1, lA1);
    GLL16(Bt + (size_t)(n0 + row0) * 768 + k0 + kk0, lB0);
    GLL16(Bt + (size_t)(n0 + row1) * 768 + k0 + kk1, lB1);
    asm volatile("s_waitcnt vmcnt(0)" ::: "memory");
    __syncthreads();
    bf16x8 af[4], bf_[4];
#pragma unroll
    for (int i = 0; i < 4; ++i) {
      af[i]  = *(const bf16x8*)(As + (wr * 64 + i * 16 + l15) * 32 + lh * 8);
      bf_[i] = *(const bf16x8*)(Bs + (wc * 64 + i * 16 + l15) * 32 + lh * 8);
    }
#pragma unroll
    for (int i = 0; i < 4; ++i)
#pragma unroll
      for (int j = 0; j < 4; ++j) acc[i][j] = MFMA16(af[i], bf_[j], acc[i][j]);
  }
#pragma unroll
  for (int j = 0; j < 4; ++j) {
    int c = n0 + wc * 64 + j * 16 + l15;
#pragma unroll
    for (int i = 0; i < 4; ++i)
#pragma unroll
      for (int r = 0; r < 4; ++r) {
        int m = m0 + wr * 64 + i * 16 + lh * 4 + r;
        C[(size_t)m * 768 + c] = acc[i][j][r];
      }
  }
}

extern "C" void kernel_launch(void* const* d_in, const int* in_sizes, int n_in,
                              void* d_out, int out_size, void* d_ws, size_t ws_size,
                              hipStream_t stream) {
  const float* x  = (const float*)d_in[0];
  const float* wq = (const float*)d_in[1];
  const float* wk = (const float*)d_in[2];
  const float* wv = (const float*)d_in[3];
  const float* op = (const float*)d_in[4];
  float* out = (float*)d_out;

  char* ws = (char*)d_ws;
  const size_t SZ = (size_t)8192 * 768 * 2;
  __bf16* xh   = (__bf16*)ws; ws += SZ;
  __bf16* xl   = (__bf16*)ws; ws += SZ;
  __bf16* wt_h = (__bf16*)ws; ws += (size_t)2304 * 768 * 2;
  __bf16* wt_l = (__bf16*)ws; ws += (size_t)2304 * 768 * 2;
  __bf16* wot  = (__bf16*)ws; ws += (size_t)768 * 768 * 2;
  __bf16* qh   = (__bf16*)ws; ws += SZ;
  __bf16* ql   = (__bf16*)ws; ws += SZ;
  __bf16* kh   = (__bf16*)ws; ws += SZ;
  __bf16* kl   = (__bf16*)ws; ws += SZ;
  __bf16* vT   = (__bf16*)ws; ws += SZ;
  __bf16* ctx  = (__bf16*)ws; ws += SZ;

  hipLaunchKernelGGL(k_conv_x, dim3(3072), dim3(256), 0, stream, x, xh, xl);
  hipLaunchKernelGGL(k_conv_w, dim3(2304), dim3(256), 0, stream,
                     wq, wk, wv, op, wt_h, wt_l, wot);
  hipLaunchKernelGGL(k_qkv_gemm, dim3(64 * 18), dim3(256), 0, stream,
                     xh, xl, wt_h, wt_l, qh, ql, kh, kl, vT);
  hipLaunchKernelGGL(k_attn, dim3(48 * 16), dim3(256), 0, stream,
                     qh, ql, kh, kl, vT, ctx);
  hipLaunchKernelGGL(k_out_gemm, dim3(64 * 6), dim3(256), 0, stream, ctx, wot, out);
}

// Round 4
// 259.903 us; speedup vs baseline: 2.7783x; 1.1088x over previous
//
#include <hip/hip_runtime.h>

typedef __bf16    bf16x8 __attribute__((ext_vector_type(8)));
typedef __bf16    bf16x4 __attribute__((ext_vector_type(4)));
typedef _Float16  f16x8  __attribute__((ext_vector_type(8)));
typedef float     f32x4  __attribute__((ext_vector_type(4)));

#define MFMA16(a,b,c)  __builtin_amdgcn_mfma_f32_16x16x32_bf16((a),(b),(c),0,0,0)
#define MFMAF16(a,b,c) __builtin_amdgcn_mfma_f32_16x16x32_f16((a),(b),(c),0,0,0)

#define AS1(p) (const __attribute__((address_space(1))) void*)(p)
#define AS3(p) (__attribute__((address_space(3))) void*)(p)
#define GLL16(g, l) __builtin_amdgcn_global_load_lds(AS1(g), AS3(l), 16, 0, 0)

__device__ __forceinline__ float fexp2(float x) {
  float r; asm("v_exp_f32 %0, %1" : "=v"(r) : "v"(x)); return r;
}

// B=4, N=2048, H=12, hd=64, D=768, M=B*N=8192
// Q stored pre-scaled by log2(e)/8 so softmax uses exp2 directly.
#define QSCALE 0.18033688011112042f

// ---------------- x -> (xh, xl) split bf16 ----------------
__global__ __launch_bounds__(256) void k_conv_x(const float* __restrict__ x,
                                                __bf16* __restrict__ xh,
                                                __bf16* __restrict__ xl) {
  int i = blockIdx.x * 256 + threadIdx.x;
  const float4* p = (const float4*)x + (size_t)i * 2;
  float4 a = p[0], b = p[1];
  float v[8] = {a.x, a.y, a.z, a.w, b.x, b.y, b.z, b.w};
  bf16x8 h, l;
#pragma unroll
  for (int j = 0; j < 8; ++j) {
    __bf16 hh = (__bf16)v[j];
    h[j] = hh;
    l[j] = (__bf16)(v[j] - (float)hh);
  }
  *(bf16x8*)(xh + (size_t)i * 8) = h;
  *(bf16x8*)(xl + (size_t)i * 8) = l;
}

// ------- weights: W[k][c] -> Wt[c][k] bf16 (hi/lo), LDS-tiled transpose -------
__global__ __launch_bounds__(256) void k_conv_w(const float* __restrict__ wq,
                                                const float* __restrict__ wk,
                                                const float* __restrict__ wv,
                                                const float* __restrict__ op,
                                                __bf16* __restrict__ wt_h,
                                                __bf16* __restrict__ wt_l,
                                                __bf16* __restrict__ wot) {
  __shared__ float tile[32][33];
  int bid = blockIdx.x;
  int m = bid / 576, rem = bid % 576;
  int tr = rem / 24, tc = rem % 24;
  const float* src = (m == 0) ? wq : (m == 1) ? wk : (m == 2) ? wv : op;
  int tx = threadIdx.x & 31, ty = threadIdx.x >> 5;
  int r0 = tr * 32, c0 = tc * 32;
#pragma unroll
  for (int j = 0; j < 4; ++j)
    tile[ty + j * 8][tx] = src[(size_t)(r0 + ty + j * 8) * 768 + c0 + tx];
  __syncthreads();
#pragma unroll
  for (int j = 0; j < 4; ++j) {
    float v = tile[tx][ty + j * 8];
    size_t o = (size_t)(c0 + ty + j * 8) * 768 + r0 + tx;
    if (m < 3) {
      size_t oo = (size_t)m * (768 * 768) + o;
      __bf16 h = (__bf16)v;
      wt_h[oo] = h;
      wt_l[oo] = (__bf16)(v - (float)h);
    } else {
      wot[o] = (__bf16)v;
    }
  }
}

// ---------------- fused QKV GEMM: dbuf 2-phase + swizzled LDS ----------------
// Q,K cols: 3-term split-bf16 compute, f16 single output. V cols: 1-term, vT out.
__global__ __launch_bounds__(256) void k_qkv_gemm(
    const __bf16* __restrict__ Ah, const __bf16* __restrict__ Al,
    const __bf16* __restrict__ Bh, const __bf16* __restrict__ Bl,
    _Float16* __restrict__ qf_o, _Float16* __restrict__ kf_o,
    __bf16* __restrict__ vT_o) {
  __shared__ __align__(16) __bf16 AsH[2][128 * 32];
  __shared__ __align__(16) __bf16 AsL[2][128 * 32];
  __shared__ __align__(16) __bf16 BsH[2][128 * 32];
  __shared__ __align__(16) __bf16 BsL[2][128 * 32];
  int t = threadIdx.x, lane = t & 63, wid = t >> 6;
  int l15 = lane & 15, lh = lane >> 4;
  int bid = blockIdx.x;
  int mt = bid & 63, nt = bid >> 6;
  int m0 = mt * 128, n0 = nt * 128;
  int wr = wid >> 1, wc = wid & 1;
  bool split = (n0 < 1536);
  f32x4 acc[4][4];
#pragma unroll
  for (int i = 0; i < 4; ++i)
#pragma unroll
    for (int j = 0; j < 4; ++j) acc[i][j] = (f32x4){0.f, 0.f, 0.f, 0.f};

  // staging: inverse-swizzled global source, linear LDS dest (rule #21)
  int row0 = t >> 2;
  int kkA = (((t & 3) ^ ((row0 >> 1) & 3)) << 3);   // swizzled 8-elem block
  char* lAH[2] = {(char*)AsH[0] + wid * 1024, (char*)AsH[1] + wid * 1024};
  char* lAL[2] = {(char*)AsL[0] + wid * 1024, (char*)AsL[1] + wid * 1024};
  char* lBH[2] = {(char*)BsH[0] + wid * 1024, (char*)BsH[1] + wid * 1024};
  char* lBL[2] = {(char*)BsL[0] + wid * 1024, (char*)BsL[1] + wid * 1024};

#define QKV_STAGE(bb, k0s) do {                                              \
    size_t a0 = (size_t)(m0 + row0) * 768 + (k0s) + kkA;                     \
    size_t a1 = a0 + (size_t)64 * 768;                                       \
    size_t b0 = (size_t)(n0 + row0) * 768 + (k0s) + kkA;                     \
    size_t b1 = b0 + (size_t)64 * 768;                                       \
    GLL16(Ah + a0, lAH[bb]); GLL16(Ah + a1, lAH[bb] + 4096);                 \
    GLL16(Bh + b0, lBH[bb]); GLL16(Bh + b1, lBH[bb] + 4096);                 \
    if (split) {                                                             \
      GLL16(Al + a0, lAL[bb]); GLL16(Al + a1, lAL[bb] + 4096);               \
      GLL16(Bl + b0, lBL[bb]); GLL16(Bl + b1, lBL[bb] + 4096);               \
    }                                                                        \
  } while (0)

  QKV_STAGE(0, 0);
  asm volatile("s_waitcnt vmcnt(0)" ::: "memory");
  __syncthreads();

  for (int tt = 0; tt < 24; ++tt) {
    int cur = tt & 1;
    if (tt < 23) QKV_STAGE(cur ^ 1, (tt + 1) * 32);

    bf16x8 af[4], alf[4], bf_[4], blf[4];
#pragma unroll
    for (int i = 0; i < 4; ++i) {
      int rowA = wr * 64 + i * 16 + l15;
      int aoff = rowA * 64 + (((lh ^ (rowA >> 1)) & 3) << 4);
      int rowB = wc * 64 + i * 16 + l15;
      int boff = rowB * 64 + (((lh ^ (rowB >> 1)) & 3) << 4);
      af[i]  = *(const bf16x8*)((char*)AsH[cur] + aoff);
      bf_[i] = *(const bf16x8*)((char*)BsH[cur] + boff);
      if (split) {
        alf[i] = *(const bf16x8*)((char*)AsL[cur] + aoff);
        blf[i] = *(const bf16x8*)((char*)BsL[cur] + boff);
      }
    }
#pragma unroll
    for (int i = 0; i < 4; ++i)
#pragma unroll
      for (int j = 0; j < 4; ++j) {
        acc[i][j] = MFMA16(af[i], bf_[j], acc[i][j]);
        if (split) {
          acc[i][j] = MFMA16(af[i], blf[j], acc[i][j]);
          acc[i][j] = MFMA16(alf[i], bf_[j], acc[i][j]);
        }
      }
    asm volatile("s_waitcnt vmcnt(0)" ::: "memory");
    __syncthreads();
  }
#undef QKV_STAGE

#pragma unroll
  for (int j = 0; j < 4; ++j) {
    int c = n0 + wc * 64 + j * 16 + l15;
    int which = c / 768; int cc = c - which * 768;
    int hh = cc >> 6, d = cc & 63;
#pragma unroll
    for (int i = 0; i < 4; ++i)
#pragma unroll
      for (int r = 0; r < 4; ++r) {
        int m = m0 + wr * 64 + i * 16 + lh * 4 + r;
        int bb = m >> 11, n = m & 2047;
        float v = acc[i][j][r];
        if (which == 2) {
          vT_o[((size_t)(bb * 12 + hh) * 64 + d) * 2048 + n] = (__bf16)v;
        } else {
          size_t o = ((size_t)(bb * 12 + hh) * 2048 + n) * 64 + d;
          if (which == 0) qf_o[o] = (_Float16)(v * QSCALE);
          else            kf_o[o] = (_Float16)v;
        }
      }
  }
}

// ---------------- causal flash attention v4 (f16 QK, dbuf stage-ahead) -------
__global__ __launch_bounds__(256) void k_attn(
    const _Float16* __restrict__ Qf, const _Float16* __restrict__ Kf,
    const __bf16* __restrict__ Vt, __bf16* __restrict__ ctx) {
  __shared__ __align__(16) _Float16 Ks[2][64 * 64];
  __shared__ __align__(16) __bf16 Vs[2][64 * 64];
  __shared__ __align__(16) __bf16 Pt[4][32 * 64];
  int t = threadIdx.x, lane = t & 63, wid = t >> 6;
  int l15 = lane & 15, lh = lane >> 4;
  int bid = blockIdx.x;
  int bh = bid % 48;
  int qt = 15 - bid / 48;                    // heavy tiles dispatch first
  int qbase = qt * 128 + wid * 32;
  size_t base = (size_t)bh * (2048 * 64);
  char* ptw = (char*)Pt[wid];

  // staging: inverse-swizzled global source, linear LDS dest
  int skey = t >> 3, sdb = t & 7;
  int ssw = (sdb ^ (skey & 7)) * 8;
  const _Float16* ksrc = Kf + base + (size_t)skey * 64 + ssw;
  const __bf16* vsrc = Vt + base + (size_t)skey * 2048 + ssw;
  char* dK[2] = {(char*)Ks[0] + wid * 1024, (char*)Ks[1] + wid * 1024};
  char* dV[2] = {(char*)Vs[0] + wid * 1024, (char*)Vs[1] + wid * 1024};

#define ATT_STAGE(bb, k0s) do {                                    \
    GLL16(ksrc + (size_t)(k0s) * 64, dK[bb]);                      \
    GLL16(ksrc + (size_t)(k0s) * 64 + 2048, dK[bb] + 4096);        \
    GLL16(vsrc + (k0s), dV[bb]);                                   \
    GLL16(vsrc + (k0s) + 32 * 2048, dV[bb] + 4096);                \
  } while (0)

  // Q fragments (pre-scaled by QSCALE in qkv epilogue)
  f16x8 qf[2][2];
#pragma unroll
  for (int i = 0; i < 2; ++i)
#pragma unroll
    for (int kk = 0; kk < 2; ++kk)
      qf[i][kk] = *(const f16x8*)(Qf + base +
          (size_t)(qbase + i * 16 + l15) * 64 + kk * 32 + lh * 8);

  f32x4 o[2][4];                              // ctx^T: row d, col q
#pragma unroll
  for (int i = 0; i < 2; ++i)
#pragma unroll
    for (int d = 0; d < 4; ++d) o[i][d] = (f32x4){0.f, 0.f, 0.f, 0.f};
  float mrun[2] = {-1e30f, -1e30f}, lrun[2] = {0.f, 0.f};

  int nIter = 2 * qt + 2;
  ATT_STAGE(0, 0);
  asm volatile("s_waitcnt vmcnt(0)" ::: "memory");
  __syncthreads();

  for (int it = 0; it < nIter; ++it) {
    int cur = it & 1;
    int k0 = it * 64;
    if (it + 1 < nIter) ATT_STAGE(cur ^ 1, k0 + 64);

    if (k0 <= qbase + 31) {
      // --- S^T = K x Q (1-term f16) ---
      f32x4 s[4][2];
#pragma unroll
      for (int j = 0; j < 4; ++j)
#pragma unroll
        for (int i = 0; i < 2; ++i) s[j][i] = (f32x4){0.f, 0.f, 0.f, 0.f};
#pragma unroll
      for (int j = 0; j < 4; ++j) {
        int kr = j * 16 + l15;
#pragma unroll
        for (int kk = 0; kk < 2; ++kk) {
          int sw = ((kk * 4 + lh) ^ (kr & 7)) << 4;
          f16x8 kf = *(const f16x8*)((char*)Ks[cur] + kr * 128 + sw);
          s[j][0] = MFMAF16(kf, qf[0][kk], s[j][0]);
          s[j][1] = MFMAF16(kf, qf[1][kk], s[j][1]);
        }
      }

      if (k0 + 63 > qbase) {                 // diagonal: causal mask
#pragma unroll
        for (int j = 0; j < 4; ++j)
#pragma unroll
          for (int i = 0; i < 2; ++i)
#pragma unroll
            for (int r = 0; r < 4; ++r) {
              int key = k0 + j * 16 + lh * 4 + r;
              int qg = qbase + i * 16 + l15;
              if (key > qg) s[j][i][r] = -1e30f;
            }
      }

      // --- online softmax: in-lane tree + 2 shuffles ---
#pragma unroll
      for (int i = 0; i < 2; ++i) {
        float m01 = fmaxf(fmaxf(s[0][i][0], s[0][i][1]), fmaxf(s[0][i][2], s[0][i][3]));
        float m23 = fmaxf(fmaxf(s[1][i][0], s[1][i][1]), fmaxf(s[1][i][2], s[1][i][3]));
        float m45 = fmaxf(fmaxf(s[2][i][0], s[2][i][1]), fmaxf(s[2][i][2], s[2][i][3]));
        float m67 = fmaxf(fmaxf(s[3][i][0], s[3][i][1]), fmaxf(s[3][i][2], s[3][i][3]));
        float mx = fmaxf(fmaxf(m01, m23), fmaxf(m45, m67));
        mx = fmaxf(mx, __shfl_xor(mx, 16));
        mx = fmaxf(mx, __shfl_xor(mx, 32));
        float mn = fmaxf(mrun[i], mx);
        float alpha = fexp2(mrun[i] - mn);
        mrun[i] = mn;
        float rsum = 0.f;
#pragma unroll
        for (int j = 0; j < 4; ++j)
#pragma unroll
          for (int r = 0; r < 4; ++r) {
            float e = fexp2(s[j][i][r] - mn);
            s[j][i][r] = e;
            rsum += e;
          }
        rsum += __shfl_xor(rsum, 16);
        rsum += __shfl_xor(rsum, 32);
        lrun[i] = lrun[i] * alpha + rsum;
#pragma unroll
        for (int d = 0; d < 4; ++d) o[i][d] *= alpha;
#pragma unroll
        for (int j = 0; j < 4; ++j) {
          bf16x4 pk = { (__bf16)s[j][i][0], (__bf16)s[j][i][1],
                        (__bf16)s[j][i][2], (__bf16)s[j][i][3] };
          int row = 16 * i + l15;
          int boff = (row * 128 + j * 32 + lh * 8) ^ ((l15 & 7) << 4);
          *(bf16x4*)(ptw + boff) = pk;
        }
      }
      asm volatile("" ::: "memory");
      bf16x8 pa[2][2];
#pragma unroll
      for (int i = 0; i < 2; ++i)
#pragma unroll
        for (int kk = 0; kk < 2; ++kk) {
          int row = 16 * i + l15;
          int boff = (row * 128 + kk * 64 + lh * 16) ^ ((l15 & 7) << 4);
          pa[i][kk] = *(const bf16x8*)(ptw + boff);
        }
      asm volatile("" ::: "memory");

      // --- ctx^T += V^T x P^T ---
#pragma unroll
      for (int dt = 0; dt < 4; ++dt) {
        int dr = dt * 16 + l15;
#pragma unroll
        for (int kk = 0; kk < 2; ++kk) {
          int sw = ((kk * 4 + lh) ^ (dr & 7)) << 4;
          bf16x8 vf = *(const bf16x8*)((char*)Vs[cur] + dr * 128 + sw);
          o[0][dt] = MFMA16(vf, pa[0][kk], o[0][dt]);
          o[1][dt] = MFMA16(vf, pa[1][kk], o[1][dt]);
        }
      }
    }
    asm volatile("s_waitcnt vmcnt(0)" ::: "memory");
    __syncthreads();
  }
#undef ATT_STAGE

  // --- epilogue: normalize, transpose via per-wave LDS, coalesced store ---
  int b = bh / 12, hh = bh - (bh / 12) * 12;
  float inv[2] = {1.f / lrun[0], 1.f / lrun[1]};
#pragma unroll
  for (int i = 0; i < 2; ++i)
#pragma unroll
    for (int dt = 0; dt < 4; ++dt) {
      bf16x4 cw = { (__bf16)(o[i][dt][0] * inv[i]), (__bf16)(o[i][dt][1] * inv[i]),
                    (__bf16)(o[i][dt][2] * inv[i]), (__bf16)(o[i][dt][3] * inv[i]) };
      int row = 16 * i + l15;
      int boff = (row * 128 + dt * 32 + lh * 8) ^ ((l15 & 7) << 4);
      *(bf16x4*)(ptw + boff) = cw;
    }
  asm volatile("" ::: "memory");
  int lr = lane >> 1, hc = lane & 1;
#pragma unroll
  for (int q16 = 0; q16 < 4; ++q16) {
    int boff = (lr * 128 + hc * 64 + q16 * 16) ^ ((lr & 7) << 4);
    bf16x8 vv = *(const bf16x8*)(ptw + boff);
    *(bf16x8*)(ctx + ((size_t)b * 2048 + qbase + lr) * 768 + hh * 64 + hc * 32 + q16 * 8) = vv;
  }
}

// ------------- out projection: dbuf 2-phase + swizzled LDS -------------
__global__ __launch_bounds__(256) void k_out_gemm(const __bf16* __restrict__ A,
                                                  const __bf16* __restrict__ Bt,
                                                  float* __restrict__ C) {
  __shared__ __align__(16) __bf16 As[2][128 * 32];
  __shared__ __align__(16) __bf16 Bs[2][128 * 32];
  int t = threadIdx.x, lane = t & 63, wid = t >> 6;
  int l15 = lane & 15, lh = lane >> 4;
  int bid = blockIdx.x;
  int mt = bid & 63, nt = bid >> 6;
  int m0 = mt * 128, n0 = nt * 128;
  int wr = wid >> 1, wc = wid & 1;
  f32x4 acc[4][4];
#pragma unroll
  for (int i = 0; i < 4; ++i)
#pragma unroll
    for (int j = 0; j < 4; ++j) acc[i][j] = (f32x4){0.f, 0.f, 0.f, 0.f};
  int row0 = t >> 2;
  int kkA = (((t & 3) ^ ((row0 >> 1) & 3)) << 3);
  char* lA[2] = {(char*)As[0] + wid * 1024, (char*)As[1] + wid * 1024};
  char* lB[2] = {(char*)Bs[0] + wid * 1024, (char*)Bs[1] + wid * 1024};

#define OUT_STAGE(bb, k0s) do {                                              \
    size_t a0 = (size_t)(m0 + row0) * 768 + (k0s) + kkA;                     \
    size_t b0 = (size_t)(n0 + row0) * 768 + (k0s) + kkA;                     \
    GLL16(A + a0, lA[bb]);  GLL16(A + a0 + (size_t)64 * 768, lA[bb] + 4096); \
    GLL16(Bt + b0, lB[bb]); GLL16(Bt + b0 + (size_t)64 * 768, lB[bb] + 4096);\
  } while (0)

  OUT_STAGE(0, 0);
  asm volatile("s_waitcnt vmcnt(0)" ::: "memory");
  __syncthreads();

  for (int tt = 0; tt < 24; ++tt) {
    int cur = tt & 1;
    if (tt < 23) OUT_STAGE(cur ^ 1, (tt + 1) * 32);
    bf16x8 af[4], bf_[4];
#pragma unroll
    for (int i = 0; i < 4; ++i) {
      int rowA = wr * 64 + i * 16 + l15;
      int aoff = rowA * 64 + (((lh ^ (rowA >> 1)) & 3) << 4);
      int rowB = wc * 64 + i * 16 + l15;
      int boff = rowB * 64 + (((lh ^ (rowB >> 1)) & 3) << 4);
      af[i]  = *(const bf16x8*)((char*)As[cur] + aoff);
      bf_[i] = *(const bf16x8*)((char*)Bs[cur] + boff);
    }
#pragma unroll
    for (int i = 0; i < 4; ++i)
#pragma unroll
      for (int j = 0; j < 4; ++j) acc[i][j] = MFMA16(af[i], bf_[j], acc[i][j]);
    asm volatile("s_waitcnt vmcnt(0)" ::: "memory");
    __syncthreads();
  }
#undef OUT_STAGE

#pragma unroll
  for (int j = 0; j < 4; ++j) {
    int c = n0 + wc * 64 + j * 16 + l15;
#pragma unroll
    for (int i = 0; i < 4; ++i)
#pragma unroll
      for (int r = 0; r < 4; ++r) {
        int m = m0 + wr * 64 + i * 16 + lh * 4 + r;
        C[(size_t)m * 768 + c] = acc[i][j][r];
      }
  }
}

extern "C" void kernel_launch(void* const* d_in, const int* in_sizes, int n_in,
                              void* d_out, int out_size, void* d_ws, size_t ws_size,
                              hipStream_t stream) {
  const float* x  = (const float*)d_in[0];
  const float* wq = (const float*)d_in[1];
  const float* wk = (const float*)d_in[2];
  const float* wv = (const float*)d_in[3];
  const float* op = (const float*)d_in[4];
  float* out = (float*)d_out;

  char* ws = (char*)d_ws;
  const size_t SZ = (size_t)8192 * 768 * 2;
  __bf16* xh     = (__bf16*)ws;    ws += SZ;
  __bf16* xl     = (__bf16*)ws;    ws += SZ;
  __bf16* wt_h   = (__bf16*)ws;    ws += (size_t)2304 * 768 * 2;
  __bf16* wt_l   = (__bf16*)ws;    ws += (size_t)2304 * 768 * 2;
  __bf16* wot    = (__bf16*)ws;    ws += (size_t)768 * 768 * 2;
  _Float16* qf   = (_Float16*)ws;  ws += SZ;
  _Float16* kf   = (_Float16*)ws;  ws += SZ;
  __bf16* vT     = (__bf16*)ws;    ws += SZ;
  __bf16* ctx    = (__bf16*)ws;    ws += SZ;

  hipLaunchKernelGGL(k_conv_x, dim3(3072), dim3(256), 0, stream, x, xh, xl);
  hipLaunchKernelGGL(k_conv_w, dim3(2304), dim3(256), 0, stream,
                     wq, wk, wv, op, wt_h, wt_l, wot);
  hipLaunchKernelGGL(k_qkv_gemm, dim3(64 * 18), dim3(256), 0, stream,
                     xh, xl, wt_h, wt_l, qf, kf, vT);
  hipLaunchKernelGGL(k_attn, dim3(48 * 16), dim3(256), 0, stream,
                     qf, kf, vT, ctx);
  hipLaunchKernelGGL(k_out_gemm, dim3(64 * 6), dim3(256), 0, stream, ctx, wot, out);
}

// Round 8
// 246.568 us; speedup vs baseline: 2.9285x; 1.0541x over previous
//
#include <hip/hip_runtime.h>

typedef __bf16    bf16x8 __attribute__((ext_vector_type(8)));
typedef _Float16  f16x8  __attribute__((ext_vector_type(8)));
typedef _Float16  f16x4  __attribute__((ext_vector_type(4)));
typedef float     f32x4  __attribute__((ext_vector_type(4)));

#define MFMA16(a,b,c)  __builtin_amdgcn_mfma_f32_16x16x32_bf16((a),(b),(c),0,0,0)
#define MFMAF16(a,b,c) __builtin_amdgcn_mfma_f32_16x16x32_f16((a),(b),(c),0,0,0)

#define AS1(p) (const __attribute__((address_space(1))) void*)(p)
#define AS3(p) (__attribute__((address_space(3))) void*)(p)
#define GLL16(g, l) __builtin_amdgcn_global_load_lds(AS1(g), AS3(l), 16, 0, 0)

__device__ __forceinline__ float fexp2(float x) {
  float r; asm("v_exp_f32 %0, %1" : "=v"(r) : "v"(x)); return r;
}

// B=4, N=2048, H=12, hd=64, D=768, M=B*N=8192
// Q stored pre-scaled by log2(e)/8 so softmax uses exp2 directly.
#define QSCALE 0.18033688011112042f

// ---------------- x -> (xh, xl) split bf16 ----------------
__global__ __launch_bounds__(256) void k_conv_x(const float* __restrict__ x,
                                                __bf16* __restrict__ xh,
                                                __bf16* __restrict__ xl) {
  int i = blockIdx.x * 256 + threadIdx.x;
  const float4* p = (const float4*)x + (size_t)i * 2;
  float4 a = p[0], b = p[1];
  float v[8] = {a.x, a.y, a.z, a.w, b.x, b.y, b.z, b.w};
  bf16x8 h, l;
#pragma unroll
  for (int j = 0; j < 8; ++j) {
    __bf16 hh = (__bf16)v[j];
    h[j] = hh;
    l[j] = (__bf16)(v[j] - (float)hh);
  }
  *(bf16x8*)(xh + (size_t)i * 8) = h;
  *(bf16x8*)(xl + (size_t)i * 8) = l;
}

// ------- weights: W[k][c] -> Wt[c][k] bf16 (hi/lo), out_proj -> f16 -------
// grid: 4 matrices x 24x24 tiles of 32x32; block 256 = (32,8)
__global__ __launch_bounds__(256) void k_conv_w(const float* __restrict__ wq,
                                                const float* __restrict__ wk,
                                                const float* __restrict__ wv,
                                                const float* __restrict__ op,
                                                __bf16* __restrict__ wt_h,
                                                __bf16* __restrict__ wt_l,
                                                _Float16* __restrict__ wot) {
  __shared__ float tile[32][33];
  int bid = blockIdx.x;
  int m = bid / 576, rem = bid % 576;
  int tr = rem / 24, tc = rem % 24;
  const float* src = (m == 0) ? wq : (m == 1) ? wk : (m == 2) ? wv : op;
  int tx = threadIdx.x & 31, ty = threadIdx.x >> 5;
  int r0 = tr * 32, c0 = tc * 32;
#pragma unroll
  for (int j = 0; j < 4; ++j)
    tile[ty + j * 8][tx] = src[(size_t)(r0 + ty + j * 8) * 768 + c0 + tx];
  __syncthreads();
#pragma unroll
  for (int j = 0; j < 4; ++j) {
    float v = tile[tx][ty + j * 8];
    size_t o = (size_t)(c0 + ty + j * 8) * 768 + r0 + tx;
    if (m < 3) {
      size_t oo = (size_t)m * (768 * 768) + o;
      __bf16 h = (__bf16)v;
      wt_h[oo] = h;
      wt_l[oo] = (__bf16)(v - (float)h);
    } else {
      wot[o] = (_Float16)v;
    }
  }
}

// ---------------- QK GEMM: 3-term split-bf16, dbuf + swizzled LDS ----------------
// cols 0..1535 (Q then K). Outputs f16 (Q pre-scaled by QSCALE).
__global__ __launch_bounds__(256) void k_qk_gemm(
    const __bf16* __restrict__ Ah, const __bf16* __restrict__ Al,
    const __bf16* __restrict__ Bh, const __bf16* __restrict__ Bl,
    _Float16* __restrict__ qf_o, _Float16* __restrict__ kf_o) {
  __shared__ __align__(16) __bf16 AsH[2][128 * 32];
  __shared__ __align__(16) __bf16 AsL[2][128 * 32];
  __shared__ __align__(16) __bf16 BsH[2][128 * 32];
  __shared__ __align__(16) __bf16 BsL[2][128 * 32];
  int t = threadIdx.x, lane = t & 63, wid = t >> 6;
  int l15 = lane & 15, lh = lane >> 4;
  int bid = blockIdx.x;
  int mt = bid & 63, nt = bid >> 6;          // 64 x 12
  int m0 = mt * 128, n0 = nt * 128;
  int wr = wid >> 1, wc = wid & 1;
  f32x4 acc[4][4];
#pragma unroll
  for (int i = 0; i < 4; ++i)
#pragma unroll
    for (int j = 0; j < 4; ++j) acc[i][j] = (f32x4){0.f, 0.f, 0.f, 0.f};

  // staging: inverse-swizzled global source, linear LDS dest (rule #21)
  int row0 = t >> 2;
  int kkA = (((t & 3) ^ ((row0 >> 1) & 3)) << 3);   // swizzled 8-elem block
  char* lAH[2] = {(char*)AsH[0] + wid * 1024, (char*)AsH[1] + wid * 1024};
  char* lAL[2] = {(char*)AsL[0] + wid * 1024, (char*)AsL[1] + wid * 1024};
  char* lBH[2] = {(char*)BsH[0] + wid * 1024, (char*)BsH[1] + wid * 1024};
  char* lBL[2] = {(char*)BsL[0] + wid * 1024, (char*)BsL[1] + wid * 1024};

#define QK_STAGE(bb, k0s) do {                                               \
    size_t a0 = (size_t)(m0 + row0) * 768 + (k0s) + kkA;                     \
    size_t a1 = a0 + (size_t)64 * 768;                                       \
    size_t b0 = (size_t)(n0 + row0) * 768 + (k0s) + kkA;                     \
    size_t b1 = b0 + (size_t)64 * 768;                                       \
    GLL16(Ah + a0, lAH[bb]); GLL16(Ah + a1, lAH[bb] + 4096);                 \
    GLL16(Bh + b0, lBH[bb]); GLL16(Bh + b1, lBH[bb] + 4096);                 \
    GLL16(Al + a0, lAL[bb]); GLL16(Al + a1, lAL[bb] + 4096);                 \
    GLL16(Bl + b0, lBL[bb]); GLL16(Bl + b1, lBL[bb] + 4096);                 \
  } while (0)

  QK_STAGE(0, 0);
  asm volatile("s_waitcnt vmcnt(0)" ::: "memory");
  __syncthreads();

  for (int tt = 0; tt < 24; ++tt) {
    int cur = tt & 1;
    if (tt < 23) QK_STAGE(cur ^ 1, (tt + 1) * 32);

    bf16x8 af[4], alf[4], bf_[4], blf[4];
#pragma unroll
    for (int i = 0; i < 4; ++i) {
      int rowA = wr * 64 + i * 16 + l15;
      int aoff = rowA * 64 + (((lh ^ (rowA >> 1)) & 3) << 4);
      int rowB = wc * 64 + i * 16 + l15;
      int boff = rowB * 64 + (((lh ^ (rowB >> 1)) & 3) << 4);
      af[i]  = *(const bf16x8*)((char*)AsH[cur] + aoff);
      alf[i] = *(const bf16x8*)((char*)AsL[cur] + aoff);
      bf_[i] = *(const bf16x8*)((char*)BsH[cur] + boff);
      blf[i] = *(const bf16x8*)((char*)BsL[cur] + boff);
    }
    __builtin_amdgcn_s_setprio(1);
#pragma unroll
    for (int i = 0; i < 4; ++i)
#pragma unroll
      for (int j = 0; j < 4; ++j) {
        acc[i][j] = MFMA16(af[i], bf_[j], acc[i][j]);
        acc[i][j] = MFMA16(af[i], blf[j], acc[i][j]);
        acc[i][j] = MFMA16(alf[i], bf_[j], acc[i][j]);
      }
    __builtin_amdgcn_s_setprio(0);
    asm volatile("s_waitcnt vmcnt(0)" ::: "memory");
    __syncthreads();
  }
#undef QK_STAGE

#pragma unroll
  for (int j = 0; j < 4; ++j) {
    int c = n0 + wc * 64 + j * 16 + l15;
    int which = c / 768; int cc = c - which * 768;
    int hh = cc >> 6, d = cc & 63;
#pragma unroll
    for (int i = 0; i < 4; ++i)
#pragma unroll
      for (int r = 0; r < 4; ++r) {
        int m = m0 + wr * 64 + i * 16 + lh * 4 + r;
        int bb = m >> 11, n = m & 2047;
        float v = acc[i][j][r];
        size_t o = ((size_t)(bb * 12 + hh) * 2048 + n) * 64 + d;
        if (which == 0) qf_o[o] = (_Float16)(v * QSCALE);
        else            kf_o[o] = (_Float16)v;
      }
  }
}

// ---------------- V GEMM: 1-term bf16, dbuf + swizzled LDS ----------------
// cols 1536..2303 of the fused weight; output V transposed [b,h,d,n] f16.
__global__ __launch_bounds__(256) void k_v_gemm(
    const __bf16* __restrict__ A, const __bf16* __restrict__ Bt,
    _Float16* __restrict__ vT_o) {
  __shared__ __align__(16) __bf16 As[2][128 * 32];
  __shared__ __align__(16) __bf16 Bs[2][128 * 32];
  int t = threadIdx.x, lane = t & 63, wid = t >> 6;
  int l15 = lane & 15, lh = lane >> 4;
  int bid = blockIdx.x;
  int mt = bid & 63, nt = bid >> 6;          // 64 x 6
  int m0 = mt * 128, n0 = 1536 + nt * 128;
  int wr = wid >> 1, wc = wid & 1;
  f32x4 acc[4][4];
#pragma unroll
  for (int i = 0; i < 4; ++i)
#pragma unroll
    for (int j = 0; j < 4; ++j) acc[i][j] = (f32x4){0.f, 0.f, 0.f, 0.f};
  int row0 = t >> 2;
  int kkA = (((t & 3) ^ ((row0 >> 1) & 3)) << 3);
  char* lA[2] = {(char*)As[0] + wid * 1024, (char*)As[1] + wid * 1024};
  char* lB[2] = {(char*)Bs[0] + wid * 1024, (char*)Bs[1] + wid * 1024};

#define V_STAGE(bb, k0s) do {                                                \
    size_t a0 = (size_t)(m0 + row0) * 768 + (k0s) + kkA;                     \
    size_t b0 = (size_t)(n0 + row0) * 768 + (k0s) + kkA;                     \
    GLL16(A + a0, lA[bb]);  GLL16(A + a0 + (size_t)64 * 768, lA[bb] + 4096); \
    GLL16(Bt + b0, lB[bb]); GLL16(Bt + b0 + (size_t)64 * 768, lB[bb] + 4096);\
  } while (0)

  V_STAGE(0, 0);
  asm volatile("s_waitcnt vmcnt(0)" ::: "memory");
  __syncthreads();

  for (int tt = 0; tt < 24; ++tt) {
    int cur = tt & 1;
    if (tt < 23) V_STAGE(cur ^ 1, (tt + 1) * 32);
    bf16x8 af[4], bf_[4];
#pragma unroll
    for (int i = 0; i < 4; ++i) {
      int rowA = wr * 64 + i * 16 + l15;
      int aoff = rowA * 64 + (((lh ^ (rowA >> 1)) & 3) << 4);
      int rowB = wc * 64 + i * 16 + l15;
      int boff = rowB * 64 + (((lh ^ (rowB >> 1)) & 3) << 4);
      af[i]  = *(const bf16x8*)((char*)As[cur] + aoff);
      bf_[i] = *(const bf16x8*)((char*)Bs[cur] + boff);
    }
    __builtin_amdgcn_s_setprio(1);
#pragma unroll
    for (int i = 0; i < 4; ++i)
#pragma unroll
      for (int j = 0; j < 4; ++j) acc[i][j] = MFMA16(af[i], bf_[j], acc[i][j]);
    __builtin_amdgcn_s_setprio(0);
    asm volatile("s_waitcnt vmcnt(0)" ::: "memory");
    __syncthreads();
  }
#undef V_STAGE

#pragma unroll
  for (int j = 0; j < 4; ++j) {
    int c = n0 + wc * 64 + j * 16 + l15;
    int cc = c - 1536;
    int hh = cc >> 6, d = cc & 63;
#pragma unroll
    for (int i = 0; i < 4; ++i)
#pragma unroll
      for (int r = 0; r < 4; ++r) {
        int m = m0 + wr * 64 + i * 16 + lh * 4 + r;
        int bb = m >> 11, n = m & 2047;
        vT_o[((size_t)(bb * 12 + hh) * 64 + d) * 2048 + n] = (_Float16)acc[i][j][r];
      }
  }
}

// ---------------- causal flash attention (all-f16 tiles, dbuf stage-ahead) -----
__global__ __launch_bounds__(256) void k_attn(
    const _Float16* __restrict__ Qf, const _Float16* __restrict__ Kf,
    const _Float16* __restrict__ Vt, _Float16* __restrict__ ctx) {
  __shared__ __align__(16) _Float16 Ks[2][64 * 64];
  __shared__ __align__(16) _Float16 Vs[2][64 * 64];
  __shared__ __align__(16) _Float16 Pt[4][32 * 64];
  int t = threadIdx.x, lane = t & 63, wid = t >> 6;
  int l15 = lane & 15, lh = lane >> 4;
  int bid = blockIdx.x;
  int bh = bid % 48;
  int qt = 15 - bid / 48;                    // heavy tiles dispatch first
  int qbase = qt * 128 + wid * 32;
  size_t base = (size_t)bh * (2048 * 64);
  char* ptw = (char*)Pt[wid];

  // staging: inverse-swizzled global source, linear LDS dest
  int skey = t >> 3, sdb = t & 7;
  int ssw = (sdb ^ (skey & 7)) * 8;
  const _Float16* ksrc = Kf + base + (size_t)skey * 64 + ssw;
  const _Float16* vsrc = Vt + base + (size_t)skey * 2048 + ssw;
  char* dK[2] = {(char*)Ks[0] + wid * 1024, (char*)Ks[1] + wid * 1024};
  char* dV[2] = {(char*)Vs[0] + wid * 1024, (char*)Vs[1] + wid * 1024};

#define ATT_STAGE(bb, k0s) do {                                    \
    GLL16(ksrc + (size_t)(k0s) * 64, dK[bb]);                      \
    GLL16(ksrc + (size_t)(k0s) * 64 + 2048, dK[bb] + 4096);        \
    GLL16(vsrc + (k0s), dV[bb]);                                   \
    GLL16(vsrc + (k0s) + 32 * 2048, dV[bb] + 4096);                \
  } while (0)

  // Q fragments (pre-scaled by QSCALE in qk epilogue)
  f16x8 qf[2][2];
#pragma unroll
  for (int i = 0; i < 2; ++i)
#pragma unroll
    for (int kk = 0; kk < 2; ++kk)
      qf[i][kk] = *(const f16x8*)(Qf + base +
          (size_t)(qbase + i * 16 + l15) * 64 + kk * 32 + lh * 8);

  f32x4 o[2][4];                              // ctx^T: row d, col q
#pragma unroll
  for (int i = 0; i < 2; ++i)
#pragma unroll
    for (int d = 0; d < 4; ++d) o[i][d] = (f32x4){0.f, 0.f, 0.f, 0.f};
  float mrun[2] = {-1e30f, -1e30f}, lrun[2] = {0.f, 0.f};

  int nIter = 2 * qt + 2;
  ATT_STAGE(0, 0);
  asm volatile("s_waitcnt vmcnt(0)" ::: "memory");
  __syncthreads();

  for (int it = 0; it < nIter; ++it) {
    int cur = it & 1;
    int k0 = it * 64;
    if (it + 1 < nIter) ATT_STAGE(cur ^ 1, k0 + 64);

    if (k0 <= qbase + 31) {
      // --- S^T = K x Q ---
      f32x4 s[4][2];
#pragma unroll
      for (int j = 0; j < 4; ++j)
#pragma unroll
        for (int i = 0; i < 2; ++i) s[j][i] = (f32x4){0.f, 0.f, 0.f, 0.f};
      __builtin_amdgcn_s_setprio(1);
#pragma unroll
      for (int j = 0; j < 4; ++j) {
        int kr = j * 16 + l15;
#pragma unroll
        for (int kk = 0; kk < 2; ++kk) {
          int sw = ((kk * 4 + lh) ^ (kr & 7)) << 4;
          f16x8 kf = *(const f16x8*)((char*)Ks[cur] + kr * 128 + sw);
          s[j][0] = MFMAF16(kf, qf[0][kk], s[j][0]);
          s[j][1] = MFMAF16(kf, qf[1][kk], s[j][1]);
        }
      }
      __builtin_amdgcn_s_setprio(0);

      if (k0 + 63 > qbase) {                 // diagonal: causal mask
#pragma unroll
        for (int j = 0; j < 4; ++j)
#pragma unroll
          for (int i = 0; i < 2; ++i)
#pragma unroll
            for (int r = 0; r < 4; ++r) {
              int key = k0 + j * 16 + lh * 4 + r;
              int qg = qbase + i * 16 + l15;
              if (key > qg) s[j][i][r] = -1e30f;
            }
      }

      // --- online softmax: in-lane tree + 2 shuffles ---
#pragma unroll
      for (int i = 0; i < 2; ++i) {
        float m01 = fmaxf(fmaxf(s[0][i][0], s[0][i][1]), fmaxf(s[0][i][2], s[0][i][3]));
        float m23 = fmaxf(fmaxf(s[1][i][0], s[1][i][1]), fmaxf(s[1][i][2], s[1][i][3]));
        float m45 = fmaxf(fmaxf(s[2][i][0], s[2][i][1]), fmaxf(s[2][i][2], s[2][i][3]));
        float m67 = fmaxf(fmaxf(s[3][i][0], s[3][i][1]), fmaxf(s[3][i][2], s[3][i][3]));
        float mx = fmaxf(fmaxf(m01, m23), fmaxf(m45, m67));
        mx = fmaxf(mx, __shfl_xor(mx, 16));
        mx = fmaxf(mx, __shfl_xor(mx, 32));
        float mn = fmaxf(mrun[i], mx);
        float alpha = fexp2(mrun[i] - mn);
        mrun[i] = mn;
        float rsum = 0.f;
#pragma unroll
        for (int j = 0; j < 4; ++j)
#pragma unroll
          for (int r = 0; r < 4; ++r) {
            float e = fexp2(s[j][i][r] - mn);
            s[j][i][r] = e;
            rsum += e;
          }
        rsum += __shfl_xor(rsum, 16);
        rsum += __shfl_xor(rsum, 32);
        lrun[i] = lrun[i] * alpha + rsum;
#pragma unroll
        for (int d = 0; d < 4; ++d) o[i][d] *= alpha;
#pragma unroll
        for (int j = 0; j < 4; ++j) {
          f16x4 pk = { (_Float16)s[j][i][0], (_Float16)s[j][i][1],
                       (_Float16)s[j][i][2], (_Float16)s[j][i][3] };
          int row = 16 * i + l15;
          int boff = (row * 128 + j * 32 + lh * 8) ^ ((l15 & 7) << 4);
          *(f16x4*)(ptw + boff) = pk;
        }
      }
      asm volatile("" ::: "memory");
      f16x8 pa[2][2];
#pragma unroll
      for (int i = 0; i < 2; ++i)
#pragma unroll
        for (int kk = 0; kk < 2; ++kk) {
          int row = 16 * i + l15;
          int boff = (row * 128 + kk * 64 + lh * 16) ^ ((l15 & 7) << 4);
          pa[i][kk] = *(const f16x8*)(ptw + boff);
        }
      asm volatile("" ::: "memory");

      // --- ctx^T += V^T x P^T ---
      __builtin_amdgcn_s_setprio(1);
#pragma unroll
      for (int dt = 0; dt < 4; ++dt) {
        int dr = dt * 16 + l15;
#pragma unroll
        for (int kk = 0; kk < 2; ++kk) {
          int sw = ((kk * 4 + lh) ^ (dr & 7)) << 4;
          f16x8 vf = *(const f16x8*)((char*)Vs[cur] + dr * 128 + sw);
          o[0][dt] = MFMAF16(vf, pa[0][kk], o[0][dt]);
          o[1][dt] = MFMAF16(vf, pa[1][kk], o[1][dt]);
        }
      }
      __builtin_amdgcn_s_setprio(0);
    }
    asm volatile("s_waitcnt vmcnt(0)" ::: "memory");
    __syncthreads();
  }
#undef ATT_STAGE

  // --- epilogue: normalize, transpose via per-wave LDS, coalesced store ---
  int b = bh / 12, hh = bh - (bh / 12) * 12;
  float inv[2] = {1.f / lrun[0], 1.f / lrun[1]};
#pragma unroll
  for (int i = 0; i < 2; ++i)
#pragma unroll
    for (int dt = 0; dt < 4; ++dt) {
      f16x4 cw = { (_Float16)(o[i][dt][0] * inv[i]), (_Float16)(o[i][dt][1] * inv[i]),
                   (_Float16)(o[i][dt][2] * inv[i]), (_Float16)(o[i][dt][3] * inv[i]) };
      int row = 16 * i + l15;
      int boff = (row * 128 + dt * 32 + lh * 8) ^ ((l15 & 7) << 4);
      *(f16x4*)(ptw + boff) = cw;
    }
  asm volatile("" ::: "memory");
  int lr = lane >> 1, hc = lane & 1;
#pragma unroll
  for (int q16 = 0; q16 < 4; ++q16) {
    int boff = (lr * 128 + hc * 64 + q16 * 16) ^ ((lr & 7) << 4);
    f16x8 vv = *(const f16x8*)(ptw + boff);
    *(f16x8*)(ctx + ((size_t)b * 2048 + qbase + lr) * 768 + hh * 64 + hc * 32 + q16 * 8) = vv;
  }
}

// ------------- out projection: f16 in, fp32 out, dbuf + swizzled LDS -------------
__global__ __launch_bounds__(256) void k_out_gemm(const _Float16* __restrict__ A,
                                                  const _Float16* __restrict__ Bt,
                                                  float* __restrict__ C) {
  __shared__ __align__(16) _Float16 As[2][128 * 32];
  __shared__ __align__(16) _Float16 Bs[2][128 * 32];
  int t = threadIdx.x, lane = t & 63, wid = t >> 6;
  int l15 = lane & 15, lh = lane >> 4;
  int bid = blockIdx.x;
  int mt = bid & 63, nt = bid >> 6;
  int m0 = mt * 128, n0 = nt * 128;
  int wr = wid >> 1, wc = wid & 1;
  f32x4 acc[4][4];
#pragma unroll
  for (int i = 0; i < 4; ++i)
#pragma unroll
    for (int j = 0; j < 4; ++j) acc[i][j] = (f32x4){0.f, 0.f, 0.f, 0.f};
  int row0 = t >> 2;
  int kkA = (((t & 3) ^ ((row0 >> 1) & 3)) << 3);
  char* lA[2] = {(char*)As[0] + wid * 1024, (char*)As[1] + wid * 1024};
  char* lB[2] = {(char*)Bs[0] + wid * 1024, (char*)Bs[1] + wid * 1024};

#define OUT_STAGE(bb, k0s) do {                                              \
    size_t a0 = (size_t)(m0 + row0) * 768 + (k0s) + kkA;                     \
    size_t b0 = (size_t)(n0 + row0) * 768 + (k0s) + kkA;                     \
    GLL16(A + a0, lA[bb]);  GLL16(A + a0 + (size_t)64 * 768, lA[bb] + 4096); \
    GLL16(Bt + b0, lB[bb]); GLL16(Bt + b0 + (size_t)64 * 768, lB[bb] + 4096);\
  } while (0)

  OUT_STAGE(0, 0);
  asm volatile("s_waitcnt vmcnt(0)" ::: "memory");
  __syncthreads();

  for (int tt = 0; tt < 24; ++tt) {
    int cur = tt & 1;
    if (tt < 23) OUT_STAGE(cur ^ 1, (tt + 1) * 32);
    f16x8 af[4], bf_[4];
#pragma unroll
    for (int i = 0; i < 4; ++i) {
      int rowA = wr * 64 + i * 16 + l15;
      int aoff = rowA * 64 + (((lh ^ (rowA >> 1)) & 3) << 4);
      int rowB = wc * 64 + i * 16 + l15;
      int boff = rowB * 64 + (((lh ^ (rowB >> 1)) & 3) << 4);
      af[i]  = *(const f16x8*)((char*)As[cur] + aoff);
      bf_[i] = *(const f16x8*)((char*)Bs[cur] + boff);
    }
    __builtin_amdgcn_s_setprio(1);
#pragma unroll
    for (int i = 0; i < 4; ++i)
#pragma unroll
      for (int j = 0; j < 4; ++j) acc[i][j] = MFMAF16(af[i], bf_[j], acc[i][j]);
    __builtin_amdgcn_s_setprio(0);
    asm volatile("s_waitcnt vmcnt(0)" ::: "memory");
    __syncthreads();
  }
#undef OUT_STAGE

#pragma unroll
  for (int j = 0; j < 4; ++j) {
    int c = n0 + wc * 64 + j * 16 + l15;
#pragma unroll
    for (int i = 0; i < 4; ++i)
#pragma unroll
      for (int r = 0; r < 4; ++r) {
        int m = m0 + wr * 64 + i * 16 + lh * 4 + r;
        C[(size_t)m * 768 + c] = acc[i][j][r];
      }
  }
}

extern "C" void kernel_launch(void* const* d_in, const int* in_sizes, int n_in,
                              void* d_out, int out_size, void* d_ws, size_t ws_size,
                              hipStream_t stream) {
  const float* x  = (const float*)d_in[0];
  const float* wq = (const float*)d_in[1];
  const float* wk = (const float*)d_in[2];
  const float* wv = (const float*)d_in[3];
  const float* op = (const float*)d_in[4];
  float* out = (float*)d_out;

  char* ws = (char*)d_ws;
  const size_t SZ = (size_t)8192 * 768 * 2;
  __bf16* xh     = (__bf16*)ws;    ws += SZ;
  __bf16* xl     = (__bf16*)ws;    ws += SZ;
  __bf16* wt_h   = (__bf16*)ws;    ws += (size_t)2304 * 768 * 2;
  __bf16* wt_l   = (__bf16*)ws;    ws += (size_t)2304 * 768 * 2;
  _Float16* wot  = (_Float16*)ws;  ws += (size_t)768 * 768 * 2;
  _Float16* qf   = (_Float16*)ws;  ws += SZ;
  _Float16* kf   = (_Float16*)ws;  ws += SZ;
  _Float16* vT   = (_Float16*)ws;  ws += SZ;
  _Float16* ctx  = (_Float16*)ws;  ws += SZ;

  hipLaunchKernelGGL(k_conv_x, dim3(3072), dim3(256), 0, stream, x, xh, xl);
  hipLaunchKernelGGL(k_conv_w, dim3(2304), dim3(256), 0, stream,
                     wq, wk, wv, op, wt_h, wt_l, wot);
  hipLaunchKernelGGL(k_qk_gemm, dim3(64 * 12), dim3(256), 0, stream,
                     xh, xl, wt_h, wt_l, qf, kf);
  hipLaunchKernelGGL(k_v_gemm, dim3(64 * 6), dim3(256), 0, stream, xh, wt_h, vT);
  hipLaunchKernelGGL(k_attn, dim3(48 * 16), dim3(256), 0, stream, qf, kf, vT, ctx);
  hipLaunchKernelGGL(k_out_gemm, dim3(64 * 6), dim3(256), 0, stream, ctx, wot, out);
}